// Round 1
// baseline (4162.995 us; speedup 1.0000x reference)
//
#include <hip/hip_runtime.h>

constexpr int Nn   = 50000;
constexpr int Ee   = 800000;
constexpr int INC  = 64;
constexpr int HC   = 128;
constexpr int ECc  = 16;
constexpr int MLPc = 256;
constexpr int NCc  = 32;
constexpr int Gg   = 512;

__device__ __forceinline__ float frelu(float v) { return v > 0.f ? v : 0.f; }

// ---------------- precompute: deg & EA (self loop = 1.0 fill) ----------------
__global__ void k_selfloop(float* __restrict__ deg, float* __restrict__ easum) {
    int n = blockIdx.x * 256 + threadIdx.x;
    if (n < Nn) {
        deg[n] = 1.0f;
        float4 one = make_float4(1.f, 1.f, 1.f, 1.f);
        float4* p = (float4*)(easum + (size_t)n * ECc);
        p[0] = one; p[1] = one; p[2] = one; p[3] = one;
    }
}

__global__ void k_edge_deg_ea(const int* __restrict__ ei, const float* __restrict__ ea,
                              float* __restrict__ deg, float* __restrict__ easum) {
    int idx = blockIdx.x * 256 + threadIdx.x;
    if (idx >= Ee * 4) return;
    int e = idx >> 2, q = idx & 3;
    int d = ei[Ee + e];                 // dst = edge_index[1][e]
    if (q == 0) atomicAdd(&deg[d], 1.0f);
    float4 v = *(const float4*)(ea + (size_t)e * ECc + q * 4);
    float* p = easum + (size_t)d * ECc + q * 4;
    atomicAdd(p + 0, v.x); atomicAdd(p + 1, v.y);
    atomicAdd(p + 2, v.z); atomicAdd(p + 3, v.w);
}

// ---------------- per-layer feature scatter: S[dst] += x[src] ----------------
template<int CIN>
__global__ void k_scatter(const int* __restrict__ ei, const float* __restrict__ x,
                          float* __restrict__ S) {
    constexpr int Q = CIN / 4;
    int idx = blockIdx.x * 256 + threadIdx.x;
    if (idx >= Ee * Q) return;
    int e = idx / Q;
    int q = idx % Q;
    int s = ei[e];
    int d = ei[Ee + e];
    float4 v = *(const float4*)(x + (size_t)s * CIN + q * 4);
    float* p = S + (size_t)d * CIN + q * 4;
    atomicAdd(p + 0, v.x); atomicAdd(p + 1, v.y);
    atomicAdd(p + 2, v.z); atomicAdd(p + 3, v.w);
}

// ---------------- layer GEMM: [deg*x | S+x | EA] @ W + deg*b, relu/BN/relu ----------------
// BM=64, BN=128, BK=16. 256 threads: tx=tid&31 -> cols tx*4; ty=tid>>5 -> rows ty*8.
template<int CIN>
__global__ __launch_bounds__(256) void k_layer(
    const float* __restrict__ x, const float* __restrict__ S,
    const float* __restrict__ easum, const float* __restrict__ deg,
    const float* __restrict__ W, const float* __restrict__ bias,
    const float* __restrict__ gamma, const float* __restrict__ beta,
    const float* __restrict__ rmean, const float* __restrict__ rvar,
    float* __restrict__ xout)
{
    constexpr int FAN = 2 * CIN + ECc;
    constexpr int KT  = FAN / 16;
    __shared__ float As[16][68];     // padded: 2-way max on write (free)
    __shared__ float Bs[16][128];
    const int row0 = blockIdx.x * 64;
    const int tid  = threadIdx.x;
    const int tx   = tid & 31, ty = tid >> 5;

    float acc[8][4];
    #pragma unroll
    for (int i = 0; i < 8; ++i)
        #pragma unroll
        for (int j = 0; j < 4; ++j) acc[i][j] = 0.f;

    for (int kt = 0; kt < KT; ++kt) {
        const int k0 = kt * 16;
        // A tile: virtual concat [deg*x | S+x | EA]; 64x16, 4 elems/thread
        #pragma unroll
        for (int i = 0; i < 4; ++i) {
            int elem = tid + i * 256;
            int r = elem >> 4, kk = elem & 15;
            int n = row0 + r;
            int gk = k0 + kk;
            float v = 0.f;
            if (n < Nn) {
                if (gk < CIN) {
                    v = deg[n] * x[(size_t)n * CIN + gk];
                } else if (gk < 2 * CIN) {
                    int k2 = gk - CIN;
                    v = S[(size_t)n * CIN + k2] + x[(size_t)n * CIN + k2];  // + self-loop x_j
                } else {
                    v = easum[(size_t)n * ECc + (gk - 2 * CIN)];
                }
            }
            As[kk][r] = v;
        }
        // B tile: 16x128, 8 elems/thread
        #pragma unroll
        for (int i = 0; i < 8; ++i) {
            int elem = tid + i * 256;
            int r = elem >> 7, c = elem & 127;
            Bs[r][c] = W[(size_t)(k0 + r) * HC + c];
        }
        __syncthreads();
        #pragma unroll
        for (int kk = 0; kk < 16; ++kk) {
            float4 a0 = *(const float4*)&As[kk][ty * 8];
            float4 a1 = *(const float4*)&As[kk][ty * 8 + 4];
            float4 b0 = *(const float4*)&Bs[kk][tx * 4];
            float av[8] = {a0.x, a0.y, a0.z, a0.w, a1.x, a1.y, a1.z, a1.w};
            float bv[4] = {b0.x, b0.y, b0.z, b0.w};
            #pragma unroll
            for (int i = 0; i < 8; ++i)
                #pragma unroll
                for (int j = 0; j < 4; ++j)
                    acc[i][j] += av[i] * bv[j];
        }
        __syncthreads();
    }

    const int coff = tx * 4;
    float4 bb = *(const float4*)(bias  + coff);
    float4 gm = *(const float4*)(gamma + coff);
    float4 bt = *(const float4*)(beta  + coff);
    float4 rm = *(const float4*)(rmean + coff);
    float4 rv = *(const float4*)(rvar  + coff);
    float i0 = rsqrtf(rv.x + 1e-5f), i1 = rsqrtf(rv.y + 1e-5f);
    float i2 = rsqrtf(rv.z + 1e-5f), i3 = rsqrtf(rv.w + 1e-5f);

    #pragma unroll
    for (int i = 0; i < 8; ++i) {
        int n = row0 + ty * 8 + i;
        if (n < Nn) {
            float dg = deg[n];
            float v0 = frelu(acc[i][0] + dg * bb.x);
            float v1 = frelu(acc[i][1] + dg * bb.y);
            float v2 = frelu(acc[i][2] + dg * bb.z);
            float v3 = frelu(acc[i][3] + dg * bb.w);
            v0 = frelu((v0 - rm.x) * i0 * gm.x + bt.x);
            v1 = frelu((v1 - rm.y) * i1 * gm.y + bt.y);
            v2 = frelu((v2 - rm.z) * i2 * gm.z + bt.z);
            v3 = frelu((v3 - rm.w) * i3 * gm.w + bt.w);
            float4 o = make_float4(v0, v1, v2, v3);
            *(float4*)(xout + (size_t)n * HC + coff) = o;
        }
    }
}

// ---------------- global add pool ----------------
__global__ void k_pool(const float* __restrict__ x, const int* __restrict__ batch,
                       float* __restrict__ pooled) {
    int idx = blockIdx.x * 256 + threadIdx.x;
    if (idx >= Nn * 32) return;
    int n = idx >> 5, q = idx & 31;
    int g = batch[n];
    float4 v = *(const float4*)(x + (size_t)n * HC + q * 4);
    float* p = pooled + (size_t)g * HC + q * 4;
    atomicAdd(p + 0, v.x); atomicAdd(p + 1, v.y);
    atomicAdd(p + 2, v.z); atomicAdd(p + 3, v.w);
}

// ---------------- Prow = pooled @ fc1_w[128:,:] + fc1_b  (G x 256) ----------------
__global__ void k_prow(const float* __restrict__ pooled, const float* __restrict__ fc1w,
                       const float* __restrict__ fc1b, float* __restrict__ prow) {
    int g = blockIdx.x;
    int j = threadIdx.x;   // 256
    __shared__ float ps[HC];
    if (j < HC) ps[j] = pooled[(size_t)g * HC + j];
    __syncthreads();
    float v = fc1b[j];
    #pragma unroll 4
    for (int k = 0; k < HC; ++k)
        v += ps[k] * fc1w[(size_t)(HC + k) * MLPc + j];
    prow[(size_t)g * MLPc + j] = v;
}

// ---------------- fused fc1 (+Prow gather, relu) + fc2 ----------------
// BM=32, BN=256, K=128. phase1: tx=tid&63 cols tx*4, ty=tid>>6 rows ty*8.
__global__ __launch_bounds__(256) void k_fc(
    const float* __restrict__ x, const float* __restrict__ prow,
    const int* __restrict__ batch, const float* __restrict__ fc1w,
    const float* __restrict__ fc2w, const float* __restrict__ fc2b,
    float* __restrict__ out)
{
    __shared__ float As[16][36];
    __shared__ float Bs[16][MLPc];
    __shared__ float Hs[32][MLPc + 4];
    const int row0 = blockIdx.x * 32;
    const int tid  = threadIdx.x;
    const int tx   = tid & 63, ty = tid >> 6;

    float acc[8][4];
    #pragma unroll
    for (int i = 0; i < 8; ++i)
        #pragma unroll
        for (int j = 0; j < 4; ++j) acc[i][j] = 0.f;

    for (int kt = 0; kt < 8; ++kt) {
        const int k0 = kt * 16;
        #pragma unroll
        for (int i = 0; i < 2; ++i) {
            int elem = tid + i * 256;
            int r = elem >> 4, kk = elem & 15;
            int n = row0 + r;
            As[kk][r] = (n < Nn) ? x[(size_t)n * HC + k0 + kk] : 0.f;
        }
        #pragma unroll
        for (int i = 0; i < 16; ++i) {
            int elem = tid + i * 256;
            int r = elem >> 8, c = elem & 255;
            Bs[r][c] = fc1w[(size_t)(k0 + r) * MLPc + c];
        }
        __syncthreads();
        #pragma unroll
        for (int kk = 0; kk < 16; ++kk) {
            float4 a0 = *(const float4*)&As[kk][ty * 8];
            float4 a1 = *(const float4*)&As[kk][ty * 8 + 4];
            float4 b0 = *(const float4*)&Bs[kk][tx * 4];
            float av[8] = {a0.x, a0.y, a0.z, a0.w, a1.x, a1.y, a1.z, a1.w};
            float bv[4] = {b0.x, b0.y, b0.z, b0.w};
            #pragma unroll
            for (int i = 0; i < 8; ++i)
                #pragma unroll
                for (int j = 0; j < 4; ++j)
                    acc[i][j] += av[i] * bv[j];
        }
        __syncthreads();
    }

    // phase 1 epilogue: h1 = relu(acc + Prow[batch[n]]) -> LDS
    #pragma unroll
    for (int i = 0; i < 8; ++i) {
        int r = ty * 8 + i;
        int n = row0 + r;
        float4 pv = make_float4(0.f, 0.f, 0.f, 0.f);
        if (n < Nn) {
            int g = batch[n];
            pv = *(const float4*)(prow + (size_t)g * MLPc + tx * 4);
        }
        float4 h;
        h.x = frelu(acc[i][0] + pv.x);
        h.y = frelu(acc[i][1] + pv.y);
        h.z = frelu(acc[i][2] + pv.z);
        h.w = frelu(acc[i][3] + pv.w);
        *(float4*)&Hs[r][tx * 4] = h;
    }
    __syncthreads();

    // phase 2: out = Hs @ fc2 + fc2_b  (32x32, 4 rows/thread)
    const int c = tid & 31, r4 = tid >> 5;   // r4 in 0..7
    float vb = fc2b[c];
    float v[4] = {vb, vb, vb, vb};
    #pragma unroll 4
    for (int k = 0; k < MLPc; ++k) {
        float w = fc2w[(size_t)k * NCc + c];
        #pragma unroll
        for (int rr = 0; rr < 4; ++rr)
            v[rr] += Hs[r4 + rr * 8][k] * w;
    }
    #pragma unroll
    for (int rr = 0; rr < 4; ++rr) {
        int n = row0 + r4 + rr * 8;
        if (n < Nn) out[(size_t)n * NCc + c] = v[rr];
    }
}

// ---------------- launch ----------------
extern "C" void kernel_launch(void* const* d_in, const int* in_sizes, int n_in,
                              void* d_out, int out_size, void* d_ws, size_t ws_size,
                              hipStream_t stream) {
    const float* x_in  = (const float*)d_in[0];
    const int*   ei    = (const int*)d_in[1];
    const float* ea    = (const float*)d_in[2];
    const int*   batch = (const int*)d_in[3];
    const float* W0 = (const float*)d_in[4];
    const float* b0 = (const float*)d_in[5];
    const float* g0 = (const float*)d_in[6];
    const float* be0 = (const float*)d_in[7];
    const float* rm0 = (const float*)d_in[8];
    const float* rv0 = (const float*)d_in[9];
    const float* W1 = (const float*)d_in[10];
    const float* b1 = (const float*)d_in[11];
    const float* g1 = (const float*)d_in[12];
    const float* be1 = (const float*)d_in[13];
    const float* rm1 = (const float*)d_in[14];
    const float* rv1 = (const float*)d_in[15];
    const float* W2 = (const float*)d_in[16];
    const float* b2 = (const float*)d_in[17];
    const float* g2 = (const float*)d_in[18];
    const float* be2 = (const float*)d_in[19];
    const float* rm2 = (const float*)d_in[20];
    const float* rv2 = (const float*)d_in[21];
    const float* fc1w = (const float*)d_in[22];
    const float* fc1b = (const float*)d_in[23];
    const float* fc2w = (const float*)d_in[24];
    const float* fc2b = (const float*)d_in[25];

    size_t off = 0;
    auto alloc = [&](size_t bytes) {
        void* p = (char*)d_ws + off;
        off += (bytes + 255) & ~(size_t)255;
        return p;
    };
    float* deg    = (float*)alloc((size_t)Nn * 4);
    float* easum  = (float*)alloc((size_t)Nn * ECc * 4);
    float* S      = (float*)alloc((size_t)Nn * HC * 4);
    float* xA     = (float*)alloc((size_t)Nn * HC * 4);
    float* xB     = (float*)alloc((size_t)Nn * HC * 4);
    float* pooled = (float*)alloc((size_t)Gg * HC * 4);
    float* prow   = (float*)alloc((size_t)Gg * MLPc * 4);

    // deg / EA (constant across layers)
    k_selfloop<<<(Nn + 255) / 256, 256, 0, stream>>>(deg, easum);
    k_edge_deg_ea<<<(Ee * 4 + 255) / 256, 256, 0, stream>>>(ei, ea, deg, easum);

    // layer 0: x_in (N x 64) -> xA
    hipMemsetAsync(S, 0, (size_t)Nn * INC * 4, stream);
    k_scatter<INC><<<(Ee * (INC / 4) + 255) / 256, 256, 0, stream>>>(ei, x_in, S);
    k_layer<INC><<<(Nn + 63) / 64, 256, 0, stream>>>(x_in, S, easum, deg,
        W0, b0, g0, be0, rm0, rv0, xA);

    // layer 1: xA -> xB
    hipMemsetAsync(S, 0, (size_t)Nn * HC * 4, stream);
    k_scatter<HC><<<(Ee * (HC / 4) + 255) / 256, 256, 0, stream>>>(ei, xA, S);
    k_layer<HC><<<(Nn + 63) / 64, 256, 0, stream>>>(xA, S, easum, deg,
        W1, b1, g1, be1, rm1, rv1, xB);

    // layer 2: xB -> xA
    hipMemsetAsync(S, 0, (size_t)Nn * HC * 4, stream);
    k_scatter<HC><<<(Ee * (HC / 4) + 255) / 256, 256, 0, stream>>>(ei, xB, S);
    k_layer<HC><<<(Nn + 63) / 64, 256, 0, stream>>>(xB, S, easum, deg,
        W2, b2, g2, be2, rm2, rv2, xA);

    // pooling + Prow
    hipMemsetAsync(pooled, 0, (size_t)Gg * HC * 4, stream);
    k_pool<<<(Nn * 32 + 255) / 256, 256, 0, stream>>>(xA, batch, pooled);
    k_prow<<<Gg, 256, 0, stream>>>(pooled, fc1w, fc1b, prow);

    // fused fc1 + fc2
    k_fc<<<(Nn + 31) / 32, 256, 0, stream>>>(xA, prow, batch, fc1w, fc2w, fc2b,
                                             (float*)d_out);
}

// Round 2
// 754.503 us; speedup vs baseline: 5.5175x; 5.5175x over previous
//
#include <hip/hip_runtime.h>

constexpr int Nn   = 50000;
constexpr int Ee   = 800000;
constexpr int INC  = 64;
constexpr int HC   = 128;
constexpr int ECc  = 16;
constexpr int MLPc = 256;
constexpr int NCc  = 32;
constexpr int Gg   = 512;

__device__ __forceinline__ float frelu(float v) { return v > 0.f ? v : 0.f; }

// ================= CSR build =================
__global__ void k_count(const int* __restrict__ ei, int* __restrict__ degi) {
    int e = blockIdx.x * 256 + threadIdx.x;
    if (e < Ee) atomicAdd(&degi[ei[Ee + e]], 1);
}

// exclusive block scan; partials[b] = block total (partials may be null)
__global__ void k_scan_block(const int* __restrict__ in, int* __restrict__ out,
                             int* __restrict__ partials, int n) {
    __shared__ int s[256];
    int i = blockIdx.x * 256 + threadIdx.x;
    int v = (i < n) ? in[i] : 0;
    s[threadIdx.x] = v;
    __syncthreads();
    #pragma unroll
    for (int off = 1; off < 256; off <<= 1) {
        int t = (threadIdx.x >= off) ? s[threadIdx.x - off] : 0;
        __syncthreads();
        s[threadIdx.x] += t;
        __syncthreads();
    }
    if (i < n) out[i] = s[threadIdx.x] - v;          // exclusive
    if (partials && threadIdx.x == 255) partials[blockIdx.x] = s[255];
}

__global__ void k_scan_add(int* __restrict__ rowptr, const int* __restrict__ partials) {
    int i = blockIdx.x * 256 + threadIdx.x;
    if (i < Nn) rowptr[i] += partials[blockIdx.x];
    if (i == 0) rowptr[Nn] = Ee;
}

__global__ void k_cursor_deg(const int* __restrict__ rowptr, int* __restrict__ cursor,
                             float* __restrict__ deg) {
    int i = blockIdx.x * 256 + threadIdx.x;
    if (i < Nn) {
        int b = rowptr[i], e = rowptr[i + 1];
        cursor[i] = b;
        deg[i] = (float)(e - b + 1);   // +1 self loop
    }
}

__global__ void k_fill(const int* __restrict__ ei, int* __restrict__ cursor,
                       int* __restrict__ csr) {
    int e = blockIdx.x * 256 + threadIdx.x;
    if (e >= Ee) return;
    int d = ei[Ee + e];
    int pos = atomicAdd(&cursor[d], 1);
    csr[pos] = e;                      // edge id
}

// easum[n] = 1.0 (self loop fill) + sum_{e: dst=n} ea[e]   (uses edge ids)
__global__ void k_ea_gather(const int* __restrict__ rowptr, const int* __restrict__ csr,
                            const float* __restrict__ ea, float* __restrict__ easum) {
    int idx = blockIdx.x * 256 + threadIdx.x;
    int n = idx >> 2, q = idx & 3;
    if (n >= Nn) return;
    float4 acc = make_float4(1.f, 1.f, 1.f, 1.f);
    int beg = rowptr[n], end = rowptr[n + 1];
    for (int p = beg; p < end; ++p) {
        int e = csr[p];
        float4 v = *(const float4*)(ea + (size_t)e * ECc + q * 4);
        acc.x += v.x; acc.y += v.y; acc.z += v.z; acc.w += v.w;
    }
    *(float4*)(easum + (size_t)n * ECc + q * 4) = acc;
}

// csr: edge id -> src node id (in place)
__global__ void k_convert(int* __restrict__ csr, const int* __restrict__ ei) {
    int p = blockIdx.x * 256 + threadIdx.x;
    if (p < Ee) csr[p] = ei[csr[p]];
}

// ================= per-layer neighbor gather: S[n] = sum x[src] =================
template<int CIN>
__global__ __launch_bounds__(256) void k_gather(
    const int* __restrict__ rowptr, const int* __restrict__ csr,
    const float* __restrict__ x, float* __restrict__ S)
{
    constexpr int TPN = CIN / 4;
    int idx = blockIdx.x * 256 + threadIdx.x;
    int n = idx / TPN, q = idx % TPN;
    if (n >= Nn) return;
    int beg = rowptr[n], end = rowptr[n + 1];
    float4 acc = make_float4(0.f, 0.f, 0.f, 0.f);
    int p = beg;
    for (; p + 1 < end; p += 2) {
        int s0 = csr[p], s1 = csr[p + 1];
        float4 v0 = *(const float4*)(x + (size_t)s0 * CIN + q * 4);
        float4 v1 = *(const float4*)(x + (size_t)s1 * CIN + q * 4);
        acc.x += v0.x + v1.x; acc.y += v0.y + v1.y;
        acc.z += v0.z + v1.z; acc.w += v0.w + v1.w;
    }
    if (p < end) {
        int s0 = csr[p];
        float4 v0 = *(const float4*)(x + (size_t)s0 * CIN + q * 4);
        acc.x += v0.x; acc.y += v0.y; acc.z += v0.z; acc.w += v0.w;
    }
    *(float4*)(S + (size_t)n * CIN + q * 4) = acc;
}

// ================= layer GEMM: [deg*x | S+x | EA] @ W + deg*b, relu/BN/relu =================
template<int CIN>
__global__ __launch_bounds__(256) void k_layer(
    const float* __restrict__ x, const float* __restrict__ S,
    const float* __restrict__ easum, const float* __restrict__ deg,
    const float* __restrict__ W, const float* __restrict__ bias,
    const float* __restrict__ gamma, const float* __restrict__ beta,
    const float* __restrict__ rmean, const float* __restrict__ rvar,
    float* __restrict__ xout)
{
    constexpr int FAN = 2 * CIN + ECc;
    constexpr int KT  = FAN / 16;
    __shared__ float As[16][68];
    __shared__ float Bs[16][128];
    const int row0 = blockIdx.x * 64;
    const int tid  = threadIdx.x;
    const int tx   = tid & 31, ty = tid >> 5;

    float acc[8][4];
    #pragma unroll
    for (int i = 0; i < 8; ++i)
        #pragma unroll
        for (int j = 0; j < 4; ++j) acc[i][j] = 0.f;

    for (int kt = 0; kt < KT; ++kt) {
        const int k0 = kt * 16;
        #pragma unroll
        for (int i = 0; i < 4; ++i) {
            int elem = tid + i * 256;
            int r = elem >> 4, kk = elem & 15;
            int n = row0 + r;
            int gk = k0 + kk;
            float v = 0.f;
            if (n < Nn) {
                if (gk < CIN) {
                    v = deg[n] * x[(size_t)n * CIN + gk];
                } else if (gk < 2 * CIN) {
                    int k2 = gk - CIN;
                    v = S[(size_t)n * CIN + k2] + x[(size_t)n * CIN + k2];
                } else {
                    v = easum[(size_t)n * ECc + (gk - 2 * CIN)];
                }
            }
            As[kk][r] = v;
        }
        #pragma unroll
        for (int i = 0; i < 8; ++i) {
            int elem = tid + i * 256;
            int r = elem >> 7, c = elem & 127;
            Bs[r][c] = W[(size_t)(k0 + r) * HC + c];
        }
        __syncthreads();
        #pragma unroll
        for (int kk = 0; kk < 16; ++kk) {
            float4 a0 = *(const float4*)&As[kk][ty * 8];
            float4 a1 = *(const float4*)&As[kk][ty * 8 + 4];
            float4 b0 = *(const float4*)&Bs[kk][tx * 4];
            float av[8] = {a0.x, a0.y, a0.z, a0.w, a1.x, a1.y, a1.z, a1.w};
            float bv[4] = {b0.x, b0.y, b0.z, b0.w};
            #pragma unroll
            for (int i = 0; i < 8; ++i)
                #pragma unroll
                for (int j = 0; j < 4; ++j)
                    acc[i][j] += av[i] * bv[j];
        }
        __syncthreads();
    }

    const int coff = tx * 4;
    float4 bb = *(const float4*)(bias  + coff);
    float4 gm = *(const float4*)(gamma + coff);
    float4 bt = *(const float4*)(beta  + coff);
    float4 rm = *(const float4*)(rmean + coff);
    float4 rv = *(const float4*)(rvar  + coff);
    float i0 = rsqrtf(rv.x + 1e-5f), i1 = rsqrtf(rv.y + 1e-5f);
    float i2 = rsqrtf(rv.z + 1e-5f), i3 = rsqrtf(rv.w + 1e-5f);

    #pragma unroll
    for (int i = 0; i < 8; ++i) {
        int n = row0 + ty * 8 + i;
        if (n < Nn) {
            float dg = deg[n];
            float v0 = frelu(acc[i][0] + dg * bb.x);
            float v1 = frelu(acc[i][1] + dg * bb.y);
            float v2 = frelu(acc[i][2] + dg * bb.z);
            float v3 = frelu(acc[i][3] + dg * bb.w);
            v0 = frelu((v0 - rm.x) * i0 * gm.x + bt.x);
            v1 = frelu((v1 - rm.y) * i1 * gm.y + bt.y);
            v2 = frelu((v2 - rm.z) * i2 * gm.z + bt.z);
            v3 = frelu((v3 - rm.w) * i3 * gm.w + bt.w);
            *(float4*)(xout + (size_t)n * HC + coff) = make_float4(v0, v1, v2, v3);
        }
    }
}

// ================= pooling: run-segmented (batch is sorted) =================
__global__ void k_pool2(const float* __restrict__ x, const int* __restrict__ batch,
                        float* __restrict__ pooled) {
    constexpr int NPG = 64;                       // nodes per 32-lane group
    int gid  = (blockIdx.x * 256 + threadIdx.x) >> 5;
    int lane = threadIdx.x & 31;
    int n0 = gid * NPG;
    if (n0 >= Nn) return;
    int nend = min(n0 + NPG, Nn);
    int curg = batch[n0];
    float4 acc = make_float4(0.f, 0.f, 0.f, 0.f);
    for (int n = n0; n < nend; ++n) {
        int g = batch[n];
        if (g != curg) {
            float* p = pooled + (size_t)curg * HC + lane * 4;
            atomicAdd(p + 0, acc.x); atomicAdd(p + 1, acc.y);
            atomicAdd(p + 2, acc.z); atomicAdd(p + 3, acc.w);
            acc = make_float4(0.f, 0.f, 0.f, 0.f);
            curg = g;
        }
        float4 v = *(const float4*)(x + (size_t)n * HC + lane * 4);
        acc.x += v.x; acc.y += v.y; acc.z += v.z; acc.w += v.w;
    }
    float* p = pooled + (size_t)curg * HC + lane * 4;
    atomicAdd(p + 0, acc.x); atomicAdd(p + 1, acc.y);
    atomicAdd(p + 2, acc.z); atomicAdd(p + 3, acc.w);
}

// ================= Prow = pooled @ fc1_w[128:,:] + fc1_b =================
__global__ void k_prow(const float* __restrict__ pooled, const float* __restrict__ fc1w,
                       const float* __restrict__ fc1b, float* __restrict__ prow) {
    int g = blockIdx.x;
    int j = threadIdx.x;
    __shared__ float ps[HC];
    if (j < HC) ps[j] = pooled[(size_t)g * HC + j];
    __syncthreads();
    float v = fc1b[j];
    #pragma unroll 4
    for (int k = 0; k < HC; ++k)
        v += ps[k] * fc1w[(size_t)(HC + k) * MLPc + j];
    prow[(size_t)g * MLPc + j] = v;
}

// ================= fused fc1 (+Prow gather, relu) + fc2 =================
__global__ __launch_bounds__(256) void k_fc(
    const float* __restrict__ x, const float* __restrict__ prow,
    const int* __restrict__ batch, const float* __restrict__ fc1w,
    const float* __restrict__ fc2w, const float* __restrict__ fc2b,
    float* __restrict__ out)
{
    __shared__ float As[16][36];
    __shared__ float Bs[16][MLPc];
    __shared__ float Hs[32][MLPc + 4];
    const int row0 = blockIdx.x * 32;
    const int tid  = threadIdx.x;
    const int tx   = tid & 63, ty = tid >> 6;

    float acc[8][4];
    #pragma unroll
    for (int i = 0; i < 8; ++i)
        #pragma unroll
        for (int j = 0; j < 4; ++j) acc[i][j] = 0.f;

    for (int kt = 0; kt < 8; ++kt) {
        const int k0 = kt * 16;
        #pragma unroll
        for (int i = 0; i < 2; ++i) {
            int elem = tid + i * 256;
            int r = elem >> 4, kk = elem & 15;
            int n = row0 + r;
            As[kk][r] = (n < Nn) ? x[(size_t)n * HC + k0 + kk] : 0.f;
        }
        #pragma unroll
        for (int i = 0; i < 16; ++i) {
            int elem = tid + i * 256;
            int r = elem >> 8, c = elem & 255;
            Bs[r][c] = fc1w[(size_t)(k0 + r) * MLPc + c];
        }
        __syncthreads();
        #pragma unroll
        for (int kk = 0; kk < 16; ++kk) {
            float4 a0 = *(const float4*)&As[kk][ty * 8];
            float4 a1 = *(const float4*)&As[kk][ty * 8 + 4];
            float4 b0 = *(const float4*)&Bs[kk][tx * 4];
            float av[8] = {a0.x, a0.y, a0.z, a0.w, a1.x, a1.y, a1.z, a1.w};
            float bv[4] = {b0.x, b0.y, b0.z, b0.w};
            #pragma unroll
            for (int i = 0; i < 8; ++i)
                #pragma unroll
                for (int j = 0; j < 4; ++j)
                    acc[i][j] += av[i] * bv[j];
        }
        __syncthreads();
    }

    #pragma unroll
    for (int i = 0; i < 8; ++i) {
        int r = ty * 8 + i;
        int n = row0 + r;
        float4 pv = make_float4(0.f, 0.f, 0.f, 0.f);
        if (n < Nn) {
            int g = batch[n];
            pv = *(const float4*)(prow + (size_t)g * MLPc + tx * 4);
        }
        float4 h;
        h.x = frelu(acc[i][0] + pv.x);
        h.y = frelu(acc[i][1] + pv.y);
        h.z = frelu(acc[i][2] + pv.z);
        h.w = frelu(acc[i][3] + pv.w);
        *(float4*)&Hs[r][tx * 4] = h;
    }
    __syncthreads();

    const int c = tid & 31, r4 = tid >> 5;
    float vb = fc2b[c];
    float v[4] = {vb, vb, vb, vb};
    #pragma unroll 4
    for (int k = 0; k < MLPc; ++k) {
        float w = fc2w[(size_t)k * NCc + c];
        #pragma unroll
        for (int rr = 0; rr < 4; ++rr)
            v[rr] += Hs[r4 + rr * 8][k] * w;
    }
    #pragma unroll
    for (int rr = 0; rr < 4; ++rr) {
        int n = row0 + r4 + rr * 8;
        if (n < Nn) out[(size_t)n * NCc + c] = v[rr];
    }
}

// ================= launch =================
extern "C" void kernel_launch(void* const* d_in, const int* in_sizes, int n_in,
                              void* d_out, int out_size, void* d_ws, size_t ws_size,
                              hipStream_t stream) {
    const float* x_in  = (const float*)d_in[0];
    const int*   ei    = (const int*)d_in[1];
    const float* ea    = (const float*)d_in[2];
    const int*   batch = (const int*)d_in[3];
    const float* W0 = (const float*)d_in[4];
    const float* b0 = (const float*)d_in[5];
    const float* g0 = (const float*)d_in[6];
    const float* be0 = (const float*)d_in[7];
    const float* rm0 = (const float*)d_in[8];
    const float* rv0 = (const float*)d_in[9];
    const float* W1 = (const float*)d_in[10];
    const float* b1 = (const float*)d_in[11];
    const float* g1 = (const float*)d_in[12];
    const float* be1 = (const float*)d_in[13];
    const float* rm1 = (const float*)d_in[14];
    const float* rv1 = (const float*)d_in[15];
    const float* W2 = (const float*)d_in[16];
    const float* b2 = (const float*)d_in[17];
    const float* g2 = (const float*)d_in[18];
    const float* be2 = (const float*)d_in[19];
    const float* rm2 = (const float*)d_in[20];
    const float* rv2 = (const float*)d_in[21];
    const float* fc1w = (const float*)d_in[22];
    const float* fc1b = (const float*)d_in[23];
    const float* fc2w = (const float*)d_in[24];
    const float* fc2b = (const float*)d_in[25];

    size_t off = 0;
    auto alloc = [&](size_t bytes) {
        void* p = (char*)d_ws + off;
        off += (bytes + 255) & ~(size_t)255;
        return p;
    };
    int*   rowptr   = (int*)alloc((size_t)(Nn + 1) * 4);
    int*   partials = (int*)alloc(256 * 4);
    float* easum    = (float*)alloc((size_t)Nn * ECc * 4);
    float* deg      = (float*)alloc((size_t)Nn * 4);
    float* S        = (float*)alloc((size_t)Nn * HC * 4);
    float* xA       = (float*)alloc((size_t)Nn * HC * 4);
    float* xB       = (float*)alloc((size_t)Nn * HC * 4);
    float* pooled   = (float*)alloc((size_t)Gg * HC * 4);
    float* prow     = (float*)alloc((size_t)Gg * MLPc * 4);

    // aliases: degi/cursor live in S (dead before first gather);
    // csr (edge ids -> src ids) lives in d_out (fully overwritten by k_fc at the end)
    int* degi   = (int*)S;
    int* cursor = (int*)((char*)S + (((size_t)Nn * 4 + 255) & ~(size_t)255));
    int* csr    = (int*)d_out;

    constexpr int NB = (Nn + 255) / 256;   // 196

    // ---- CSR build ----
    hipMemsetAsync(degi, 0, (size_t)Nn * 4, stream);
    k_count<<<(Ee + 255) / 256, 256, 0, stream>>>(ei, degi);
    k_scan_block<<<NB, 256, 0, stream>>>(degi, rowptr, partials, Nn);
    k_scan_block<<<1, 256, 0, stream>>>(partials, partials, nullptr, NB);
    k_scan_add<<<NB, 256, 0, stream>>>(rowptr, partials);
    k_cursor_deg<<<NB, 256, 0, stream>>>(rowptr, cursor, deg);
    k_fill<<<(Ee + 255) / 256, 256, 0, stream>>>(ei, cursor, csr);
    k_ea_gather<<<(Nn * 4 + 255) / 256, 256, 0, stream>>>(rowptr, csr, ea, easum);
    k_convert<<<(Ee + 255) / 256, 256, 0, stream>>>(csr, ei);

    // ---- layer 0 ----
    k_gather<INC><<<(Nn * (INC / 4) + 255) / 256, 256, 0, stream>>>(rowptr, csr, x_in, S);
    k_layer<INC><<<(Nn + 63) / 64, 256, 0, stream>>>(x_in, S, easum, deg,
        W0, b0, g0, be0, rm0, rv0, xA);

    // ---- layer 1 ----
    k_gather<HC><<<(Nn * (HC / 4) + 255) / 256, 256, 0, stream>>>(rowptr, csr, xA, S);
    k_layer<HC><<<(Nn + 63) / 64, 256, 0, stream>>>(xA, S, easum, deg,
        W1, b1, g1, be1, rm1, rv1, xB);

    // ---- layer 2 ----
    k_gather<HC><<<(Nn * (HC / 4) + 255) / 256, 256, 0, stream>>>(rowptr, csr, xB, S);
    k_layer<HC><<<(Nn + 63) / 64, 256, 0, stream>>>(xB, S, easum, deg,
        W2, b2, g2, be2, rm2, rv2, xA);

    // ---- pool + Prow ----
    hipMemsetAsync(pooled, 0, (size_t)Gg * HC * 4, stream);
    k_pool2<<<((Nn + 63) / 64 * 32 + 255) / 256, 256, 0, stream>>>(xA, batch, pooled);
    k_prow<<<Gg, 256, 0, stream>>>(pooled, fc1w, fc1b, prow);

    // ---- fused fc1 + fc2 ----
    k_fc<<<(Nn + 31) / 32, 256, 0, stream>>>(xA, prow, batch, fc1w, fc2w, fc2b,
                                             (float*)d_out);
}

// Round 3
// 458.833 us; speedup vs baseline: 9.0730x; 1.6444x over previous
//
#include <hip/hip_runtime.h>

constexpr int Nn   = 50000;
constexpr int Ee   = 800000;
constexpr int INC  = 64;
constexpr int HC   = 128;
constexpr int ECc  = 16;
constexpr int MLPc = 256;
constexpr int NCc  = 32;
constexpr int Gg   = 512;
constexpr int Mpad = 50048;          // 391*128

typedef __attribute__((ext_vector_type(8))) short short8;
typedef __attribute__((ext_vector_type(4))) short short4v;
typedef __attribute__((ext_vector_type(4))) float f32x4;

__device__ __forceinline__ float frelu(float v) { return v > 0.f ? v : 0.f; }

__device__ __forceinline__ short f2bf(float f) {
    unsigned u = __float_as_uint(f);
    unsigned r = (u + 0x7fffu + ((u >> 16) & 1u)) >> 16;
    return (short)r;
}
__device__ __forceinline__ float bf2f(short s) {
    return __uint_as_float(((unsigned)(unsigned short)s) << 16);
}

// ================= CSR build =================
__global__ void k_count(const int* __restrict__ ei, int* __restrict__ degi) {
    int e = blockIdx.x * 256 + threadIdx.x;
    if (e < Ee) atomicAdd(&degi[ei[Ee + e]], 1);
}

__global__ void k_scan_block(const int* __restrict__ in, int* __restrict__ out,
                             int* __restrict__ partials, int n) {
    __shared__ int s[256];
    int i = blockIdx.x * 256 + threadIdx.x;
    int v = (i < n) ? in[i] : 0;
    s[threadIdx.x] = v;
    __syncthreads();
    #pragma unroll
    for (int off = 1; off < 256; off <<= 1) {
        int t = (threadIdx.x >= off) ? s[threadIdx.x - off] : 0;
        __syncthreads();
        s[threadIdx.x] += t;
        __syncthreads();
    }
    if (i < n) out[i] = s[threadIdx.x] - v;
    if (partials && threadIdx.x == 255) partials[blockIdx.x] = s[255];
}

__global__ void k_scan_add(int* __restrict__ rowptr, const int* __restrict__ partials) {
    int i = blockIdx.x * 256 + threadIdx.x;
    if (i < Nn) rowptr[i] += partials[blockIdx.x];
    if (i == 0) rowptr[Nn] = Ee;
}

__global__ void k_cursor_deg(const int* __restrict__ rowptr, int* __restrict__ cursor,
                             float* __restrict__ deg) {
    int i = blockIdx.x * 256 + threadIdx.x;
    if (i < Nn) {
        int b = rowptr[i], e = rowptr[i + 1];
        cursor[i] = b;
        deg[i] = (float)(e - b + 1);   // +1 self loop
    }
}

__global__ void k_fill(const int* __restrict__ ei, int* __restrict__ cursor,
                       int* __restrict__ csr) {
    int e = blockIdx.x * 256 + threadIdx.x;
    if (e >= Ee) return;
    int d = ei[Ee + e];
    int pos = atomicAdd(&cursor[d], 1);
    csr[pos] = e;
}

__global__ void k_ea_gather(const int* __restrict__ rowptr, const int* __restrict__ csr,
                            const float* __restrict__ ea, float* __restrict__ easum) {
    int idx = blockIdx.x * 256 + threadIdx.x;
    int n = idx >> 2, q = idx & 3;
    if (n >= Nn) return;
    float4 acc = make_float4(1.f, 1.f, 1.f, 1.f);
    int beg = rowptr[n], end = rowptr[n + 1];
    for (int p = beg; p < end; ++p) {
        int e = csr[p];
        float4 v = *(const float4*)(ea + (size_t)e * ECc + q * 4);
        acc.x += v.x; acc.y += v.y; acc.z += v.z; acc.w += v.w;
    }
    *(float4*)(easum + (size_t)n * ECc + q * 4) = acc;
}

__global__ void k_convert(int* __restrict__ csr, const int* __restrict__ ei) {
    int p = blockIdx.x * 256 + threadIdx.x;
    if (p < Ee) csr[p] = ei[csr[p]];
}

// ================= weight transpose + bf16 =================
// WT[c][k] = bf16(W[k][c]), zero-padded k in [K, KP)
__global__ void k_tbf(const float* __restrict__ W, short* __restrict__ WT,
                      int K, int Ncols, int KP) {
    int idx = blockIdx.x * 256 + threadIdx.x;
    int c = idx / KP, k = idx % KP;
    if (c >= Ncols) return;
    WT[(size_t)c * KP + k] = (k < K) ? f2bf(W[(size_t)k * Ncols + c]) : (short)0;
}

// ================= gather + A-build: A[n] = bf16[deg*x | S+x | EA | 0pad] =================
template<int CIN, int KP>
__global__ __launch_bounds__(256) void k_gather_prep(
    const int* __restrict__ rowptr, const int* __restrict__ csr,
    const float* __restrict__ x, const float* __restrict__ easum,
    const float* __restrict__ deg, short* __restrict__ A)
{
    constexpr int TPN = CIN / 4;
    int idx = blockIdx.x * 256 + threadIdx.x;
    int n = idx / TPN, q = idx % TPN;
    if (n >= Nn) return;
    int beg = rowptr[n], end = rowptr[n + 1];
    float4 acc = make_float4(0.f, 0.f, 0.f, 0.f);
    int p = beg;
    for (; p + 1 < end; p += 2) {
        int s0 = csr[p], s1 = csr[p + 1];
        float4 v0 = *(const float4*)(x + (size_t)s0 * CIN + q * 4);
        float4 v1 = *(const float4*)(x + (size_t)s1 * CIN + q * 4);
        acc.x += v0.x + v1.x; acc.y += v0.y + v1.y;
        acc.z += v0.z + v1.z; acc.w += v0.w + v1.w;
    }
    if (p < end) {
        int s0 = csr[p];
        float4 v0 = *(const float4*)(x + (size_t)s0 * CIN + q * 4);
        acc.x += v0.x; acc.y += v0.y; acc.z += v0.z; acc.w += v0.w;
    }
    float4 xv = *(const float4*)(x + (size_t)n * CIN + q * 4);
    float dg = deg[n];
    short* Ar = A + (size_t)n * KP;
    short4v h;
    h[0] = f2bf(dg * xv.x); h[1] = f2bf(dg * xv.y);
    h[2] = f2bf(dg * xv.z); h[3] = f2bf(dg * xv.w);
    *(short4v*)(Ar + q * 4) = h;
    h[0] = f2bf(acc.x + xv.x); h[1] = f2bf(acc.y + xv.y);
    h[2] = f2bf(acc.z + xv.z); h[3] = f2bf(acc.w + xv.w);
    *(short4v*)(Ar + CIN + q * 4) = h;
    if (q < 4) {
        float4 e4 = *(const float4*)(easum + (size_t)n * ECc + q * 4);
        h[0] = f2bf(e4.x); h[1] = f2bf(e4.y); h[2] = f2bf(e4.z); h[3] = f2bf(e4.w);
        *(short4v*)(Ar + 2 * CIN + q * 4) = h;
        short4v z; z[0] = 0; z[1] = 0; z[2] = 0; z[3] = 0;
        *(short4v*)(Ar + 2 * CIN + 16 + q * 4) = z;     // K padding
    }
}

// ================= layer GEMM (MFMA, LDS-free): C = A @ WT^T; BN/relu epilogue =================
template<int KP, bool OUTBF>
__global__ __launch_bounds__(256) void k_layer_mfma(
    const short* __restrict__ A, const short* __restrict__ WT,
    const float* __restrict__ deg, const float* __restrict__ bias,
    const float* __restrict__ gamma, const float* __restrict__ beta,
    const float* __restrict__ rmean, const float* __restrict__ rvar,
    float* __restrict__ xoutf, short* __restrict__ xoutb)
{
    const int wv = threadIdx.x >> 6, lane = threadIdx.x & 63;
    const int lr = lane & 15, lk = lane >> 4;
    const int row0 = blockIdx.x * 128 + wv * 32;
    const short* Ap0 = A + (size_t)(row0 + lr) * KP + lk * 8;
    const short* Ap1 = Ap0 + (size_t)16 * KP;
    const short* Bp  = WT + (size_t)lr * KP + lk * 8;

    f32x4 acc[2][8];
    #pragma unroll
    for (int i = 0; i < 2; ++i)
        #pragma unroll
        for (int j = 0; j < 8; ++j) acc[i][j] = (f32x4){0.f, 0.f, 0.f, 0.f};

    #pragma unroll 2
    for (int k0 = 0; k0 < KP; k0 += 32) {
        short8 a0 = *(const short8*)(Ap0 + k0);
        short8 a1 = *(const short8*)(Ap1 + k0);
        #pragma unroll
        for (int j = 0; j < 8; ++j) {
            short8 b = *(const short8*)(Bp + (size_t)j * 16 * KP + k0);
            acc[0][j] = __builtin_amdgcn_mfma_f32_16x16x32_bf16(a0, b, acc[0][j], 0, 0, 0);
            acc[1][j] = __builtin_amdgcn_mfma_f32_16x16x32_bf16(a1, b, acc[1][j], 0, 0, 0);
        }
    }

    #pragma unroll
    for (int rf = 0; rf < 2; ++rf) {
        int rbase = row0 + rf * 16 + lk * 4;
        float dgs[4];
        #pragma unroll
        for (int i = 0; i < 4; ++i)
            dgs[i] = (rbase + i < Nn) ? deg[rbase + i] : 0.f;
        #pragma unroll
        for (int j = 0; j < 8; ++j) {
            int c = j * 16 + lr;
            float bb = bias[c], gm = gamma[c], bt = beta[c], rm = rmean[c];
            float inv = rsqrtf(rvar[c] + 1e-5f);
            #pragma unroll
            for (int i = 0; i < 4; ++i) {
                int r = rbase + i;
                if (r < Nn) {
                    float v = frelu(acc[rf][j][i] + dgs[i] * bb);
                    v = frelu((v - rm) * inv * gm + bt);
                    if (OUTBF) xoutb[(size_t)r * HC + c] = f2bf(v);
                    else       xoutf[(size_t)r * HC + c] = v;
                }
            }
        }
    }
}

// ================= pooling (bf16 x, run-segmented) =================
__global__ void k_pool2(const short* __restrict__ xbf, const int* __restrict__ batch,
                        float* __restrict__ pooled) {
    constexpr int NPG = 64;
    int gid  = (blockIdx.x * 256 + threadIdx.x) >> 5;
    int lane = threadIdx.x & 31;
    int n0 = gid * NPG;
    if (n0 >= Nn) return;
    int nend = min(n0 + NPG, Nn);
    int curg = batch[n0];
    float4 acc = make_float4(0.f, 0.f, 0.f, 0.f);
    for (int n = n0; n < nend; ++n) {
        int g = batch[n];
        if (g != curg) {
            float* p = pooled + (size_t)curg * HC + lane * 4;
            atomicAdd(p + 0, acc.x); atomicAdd(p + 1, acc.y);
            atomicAdd(p + 2, acc.z); atomicAdd(p + 3, acc.w);
            acc = make_float4(0.f, 0.f, 0.f, 0.f);
            curg = g;
        }
        short4v v = *(const short4v*)(xbf + (size_t)n * HC + lane * 4);
        acc.x += bf2f(v[0]); acc.y += bf2f(v[1]);
        acc.z += bf2f(v[2]); acc.w += bf2f(v[3]);
    }
    float* p = pooled + (size_t)curg * HC + lane * 4;
    atomicAdd(p + 0, acc.x); atomicAdd(p + 1, acc.y);
    atomicAdd(p + 2, acc.z); atomicAdd(p + 3, acc.w);
}

// ================= Prow = pooled @ fc1_w[128:,:] + fc1_b (f32) =================
__global__ void k_prow(const float* __restrict__ pooled, const float* __restrict__ fc1w,
                       const float* __restrict__ fc1b, float* __restrict__ prow) {
    int g = blockIdx.x;
    int j = threadIdx.x;
    __shared__ float ps[HC];
    if (j < HC) ps[j] = pooled[(size_t)g * HC + j];
    __syncthreads();
    float v = fc1b[j];
    #pragma unroll 4
    for (int k = 0; k < HC; ++k)
        v += ps[k] * fc1w[(size_t)(HC + k) * MLPc + j];
    prow[(size_t)g * MLPc + j] = v;
}

// ================= fused fc1+fc2 (MFMA) =================
__global__ __launch_bounds__(256) void k_fc_mfma(
    const short* __restrict__ xbf, const float* __restrict__ prow,
    const int* __restrict__ batch, const short* __restrict__ fc1wT,  // [256][128]
    const short* __restrict__ fc2wT,                                  // [32][256]
    const float* __restrict__ fc2b, float* __restrict__ out)
{
    __shared__ short h1s[64][264];
    const int wv = threadIdx.x >> 6, lane = threadIdx.x & 63;
    const int lr = lane & 15, lk = lane >> 4;
    const int row0 = blockIdx.x * 64;
    const int rw = row0 + wv * 16;

    // ---- phase 1: h1 = relu(xbf @ fc1w[0:128] + prow[batch]) ----
    f32x4 acc[16];
    #pragma unroll
    for (int j = 0; j < 16; ++j) acc[j] = (f32x4){0.f, 0.f, 0.f, 0.f};
    const short* Ap = xbf + (size_t)(rw + lr) * HC + lk * 8;
    #pragma unroll 2
    for (int k0 = 0; k0 < 128; k0 += 32) {
        short8 a = *(const short8*)(Ap + k0);
        #pragma unroll
        for (int j = 0; j < 16; ++j) {
            short8 b = *(const short8*)(fc1wT + (size_t)(j * 16 + lr) * 128 + k0 + lk * 8);
            acc[j] = __builtin_amdgcn_mfma_f32_16x16x32_bf16(a, b, acc[j], 0, 0, 0);
        }
    }
    int rbase = rw + lk * 4;
    int gg[4];
    #pragma unroll
    for (int i = 0; i < 4; ++i)
        gg[i] = (rbase + i < Nn) ? batch[rbase + i] : 0;
    #pragma unroll
    for (int j = 0; j < 16; ++j) {
        int c = j * 16 + lr;
        #pragma unroll
        for (int i = 0; i < 4; ++i) {
            float pv = prow[(size_t)gg[i] * MLPc + c];
            h1s[rbase - row0 + i][c] = f2bf(frelu(acc[j][i] + pv));
        }
    }
    __syncthreads();

    // ---- phase 2: out = h1 @ fc2w + fc2b ----
    f32x4 acc2[2];
    acc2[0] = (f32x4){0.f, 0.f, 0.f, 0.f};
    acc2[1] = (f32x4){0.f, 0.f, 0.f, 0.f};
    #pragma unroll 2
    for (int k0 = 0; k0 < 256; k0 += 32) {
        short8 a = *(const short8*)(&h1s[wv * 16 + lr][k0 + lk * 8]);
        #pragma unroll
        for (int cf = 0; cf < 2; ++cf) {
            short8 b = *(const short8*)(fc2wT + (size_t)(cf * 16 + lr) * 256 + k0 + lk * 8);
            acc2[cf] = __builtin_amdgcn_mfma_f32_16x16x32_bf16(a, b, acc2[cf], 0, 0, 0);
        }
    }
    #pragma unroll
    for (int cf = 0; cf < 2; ++cf) {
        int c = cf * 16 + lr;
        float bb = fc2b[c];
        #pragma unroll
        for (int i = 0; i < 4; ++i) {
            int r = rbase + i;
            if (r < Nn) out[(size_t)r * NCc + c] = acc2[cf][i] + bb;
        }
    }
}

// ================= launch =================
extern "C" void kernel_launch(void* const* d_in, const int* in_sizes, int n_in,
                              void* d_out, int out_size, void* d_ws, size_t ws_size,
                              hipStream_t stream) {
    const float* x_in  = (const float*)d_in[0];
    const int*   ei    = (const int*)d_in[1];
    const float* ea    = (const float*)d_in[2];
    const int*   batch = (const int*)d_in[3];
    const float* W0 = (const float*)d_in[4];
    const float* b0 = (const float*)d_in[5];
    const float* g0 = (const float*)d_in[6];
    const float* be0 = (const float*)d_in[7];
    const float* rm0 = (const float*)d_in[8];
    const float* rv0 = (const float*)d_in[9];
    const float* W1 = (const float*)d_in[10];
    const float* b1 = (const float*)d_in[11];
    const float* g1 = (const float*)d_in[12];
    const float* be1 = (const float*)d_in[13];
    const float* rm1 = (const float*)d_in[14];
    const float* rv1 = (const float*)d_in[15];
    const float* W2 = (const float*)d_in[16];
    const float* b2 = (const float*)d_in[17];
    const float* g2 = (const float*)d_in[18];
    const float* be2 = (const float*)d_in[19];
    const float* rm2 = (const float*)d_in[20];
    const float* rv2 = (const float*)d_in[21];
    const float* fc1w = (const float*)d_in[22];
    const float* fc1b = (const float*)d_in[23];
    const float* fc2w = (const float*)d_in[24];
    const float* fc2b = (const float*)d_in[25];

    size_t off = 0;
    auto alloc = [&](size_t bytes) {
        void* p = (char*)d_ws + off;
        off += (bytes + 255) & ~(size_t)255;
        return p;
    };
    int*   rowptr   = (int*)alloc((size_t)(Nn + 1) * 4);
    int*   partials = (int*)alloc(256 * 4);
    float* easum    = (float*)alloc((size_t)Nn * ECc * 4);
    float* deg      = (float*)alloc((size_t)Nn * 4);
    int*   degi     = (int*)alloc((size_t)Nn * 4);
    int*   cursor   = (int*)alloc((size_t)Nn * 4);
    short* A        = (short*)alloc((size_t)Mpad * 288 * 2);
    float* xA       = (float*)alloc((size_t)Nn * HC * 4);
    short* xbf      = (short*)alloc((size_t)Mpad * HC * 2);
    short* WT0      = (short*)alloc((size_t)HC * 160 * 2);
    short* WT1      = (short*)alloc((size_t)HC * 288 * 2);
    short* WT2      = (short*)alloc((size_t)HC * 288 * 2);
    short* fc1wT    = (short*)alloc((size_t)MLPc * 128 * 2);
    short* fc2wT    = (short*)alloc((size_t)NCc * 256 * 2);
    float* pooled   = (float*)alloc((size_t)Gg * HC * 4);
    float* prow     = (float*)alloc((size_t)Gg * MLPc * 4);

    int* csr = (int*)d_out;   // 3.2MB in 6.4MB d_out; dead before k_fc writes out

    constexpr int NB = (Nn + 255) / 256;

    // ---- CSR build ----
    hipMemsetAsync(degi, 0, (size_t)Nn * 4, stream);
    k_count<<<(Ee + 255) / 256, 256, 0, stream>>>(ei, degi);
    k_scan_block<<<NB, 256, 0, stream>>>(degi, rowptr, partials, Nn);
    k_scan_block<<<1, 256, 0, stream>>>(partials, partials, nullptr, NB);
    k_scan_add<<<NB, 256, 0, stream>>>(rowptr, partials);
    k_cursor_deg<<<NB, 256, 0, stream>>>(rowptr, cursor, deg);
    k_fill<<<(Ee + 255) / 256, 256, 0, stream>>>(ei, cursor, csr);
    k_ea_gather<<<(Nn * 4 + 255) / 256, 256, 0, stream>>>(rowptr, csr, ea, easum);
    k_convert<<<(Ee + 255) / 256, 256, 0, stream>>>(csr, ei);

    // ---- weight prep (bf16 transposed) ----
    k_tbf<<<(HC * 160 + 255) / 256, 256, 0, stream>>>(W0, WT0, 144, HC, 160);
    k_tbf<<<(HC * 288 + 255) / 256, 256, 0, stream>>>(W1, WT1, 272, HC, 288);
    k_tbf<<<(HC * 288 + 255) / 256, 256, 0, stream>>>(W2, WT2, 272, HC, 288);
    k_tbf<<<(MLPc * 128 + 255) / 256, 256, 0, stream>>>(fc1w, fc1wT, 128, MLPc, 128);
    k_tbf<<<(NCc * 256 + 255) / 256, 256, 0, stream>>>(fc2w, fc2wT, 256, NCc, 256);

    const int LGRID = (Mpad + 127) / 128;   // 391

    // ---- layer 0 ----
    k_gather_prep<INC, 160><<<(Nn * (INC / 4) + 255) / 256, 256, 0, stream>>>(
        rowptr, csr, x_in, easum, deg, A);
    k_layer_mfma<160, false><<<LGRID, 256, 0, stream>>>(A, WT0, deg,
        b0, g0, be0, rm0, rv0, xA, nullptr);

    // ---- layer 1 (overwrite xA: k_layer reads only A) ----
    k_gather_prep<HC, 288><<<(Nn * (HC / 4) + 255) / 256, 256, 0, stream>>>(
        rowptr, csr, xA, easum, deg, A);
    k_layer_mfma<288, false><<<LGRID, 256, 0, stream>>>(A, WT1, deg,
        b1, g1, be1, rm1, rv1, xA, nullptr);

    // ---- layer 2 (bf16 output only) ----
    k_gather_prep<HC, 288><<<(Nn * (HC / 4) + 255) / 256, 256, 0, stream>>>(
        rowptr, csr, xA, easum, deg, A);
    k_layer_mfma<288, true><<<LGRID, 256, 0, stream>>>(A, WT2, deg,
        b2, g2, be2, rm2, rv2, nullptr, xbf);

    // ---- pool + Prow ----
    hipMemsetAsync(pooled, 0, (size_t)Gg * HC * 4, stream);
    k_pool2<<<((Nn + 63) / 64 * 32 + 255) / 256, 256, 0, stream>>>(xbf, batch, pooled);
    k_prow<<<Gg, 256, 0, stream>>>(pooled, fc1w, fc1b, prow);

    // ---- fused fc1 + fc2 ----
    k_fc_mfma<<<(Mpad + 63) / 64, 256, 0, stream>>>(xbf, prow, batch, fc1wT, fc2wT,
                                                    fc2b, (float*)d_out);
}

// Round 4
// 403.377 us; speedup vs baseline: 10.3204x; 1.1375x over previous
//
#include <hip/hip_runtime.h>

constexpr int Nn   = 50000;
constexpr int Ee   = 800000;
constexpr int INC  = 64;
constexpr int HC   = 128;
constexpr int ECc  = 16;
constexpr int MLPc = 256;
constexpr int NCc  = 32;
constexpr int Gg   = 512;
constexpr int Mpad = 50048;          // 391*128

typedef __attribute__((ext_vector_type(8))) short short8;
typedef __attribute__((ext_vector_type(4))) short short4v;
typedef __attribute__((ext_vector_type(4))) float f32x4;

__device__ __forceinline__ float frelu(float v) { return v > 0.f ? v : 0.f; }

__device__ __forceinline__ short f2bf(float f) {
    unsigned u = __float_as_uint(f);
    unsigned r = (u + 0x7fffu + ((u >> 16) & 1u)) >> 16;
    return (short)r;
}
__device__ __forceinline__ float bf2f(short s) {
    return __uint_as_float(((unsigned)(unsigned short)s) << 16);
}

// ================= CSR build =================
__global__ void k_count(const int* __restrict__ ei, int* __restrict__ degi) {
    int e = blockIdx.x * 256 + threadIdx.x;
    if (e < Ee) atomicAdd(&degi[ei[Ee + e]], 1);
}

__global__ void k_scan_block(const int* __restrict__ in, int* __restrict__ out,
                             int* __restrict__ partials, int n) {
    __shared__ int s[256];
    int i = blockIdx.x * 256 + threadIdx.x;
    int v = (i < n) ? in[i] : 0;
    s[threadIdx.x] = v;
    __syncthreads();
    #pragma unroll
    for (int off = 1; off < 256; off <<= 1) {
        int t = (threadIdx.x >= off) ? s[threadIdx.x - off] : 0;
        __syncthreads();
        s[threadIdx.x] += t;
        __syncthreads();
    }
    if (i < n) out[i] = s[threadIdx.x] - v;
    if (partials && threadIdx.x == 255) partials[blockIdx.x] = s[255];
}

__global__ void k_scan_add(int* __restrict__ rowptr, const int* __restrict__ partials) {
    int i = blockIdx.x * 256 + threadIdx.x;
    if (i < Nn) rowptr[i] += partials[blockIdx.x];
    if (i == 0) rowptr[Nn] = Ee;
}

__global__ void k_cursor_deg(const int* __restrict__ rowptr, int* __restrict__ cursor,
                             float* __restrict__ deg) {
    int i = blockIdx.x * 256 + threadIdx.x;
    if (i < Nn) {
        int b = rowptr[i], e = rowptr[i + 1];
        cursor[i] = b;
        deg[i] = (float)(e - b + 1);   // +1 self loop
    }
}

__global__ void k_fill(const int* __restrict__ ei, int* __restrict__ cursor,
                       int* __restrict__ csr) {
    int e = blockIdx.x * 256 + threadIdx.x;
    if (e >= Ee) return;
    int d = ei[Ee + e];
    int pos = atomicAdd(&cursor[d], 1);
    csr[pos] = e;
}

__global__ void k_ea_gather(const int* __restrict__ rowptr, const int* __restrict__ csr,
                            const float* __restrict__ ea, float* __restrict__ easum) {
    int idx = blockIdx.x * 256 + threadIdx.x;
    int n = idx >> 2, q = idx & 3;
    if (n >= Nn) return;
    float4 acc = make_float4(1.f, 1.f, 1.f, 1.f);
    int beg = rowptr[n], end = rowptr[n + 1];
    for (int p = beg; p < end; ++p) {
        int e = csr[p];
        float4 v = *(const float4*)(ea + (size_t)e * ECc + q * 4);
        acc.x += v.x; acc.y += v.y; acc.z += v.z; acc.w += v.w;
    }
    *(float4*)(easum + (size_t)n * ECc + q * 4) = acc;
}

__global__ void k_convert(int* __restrict__ csr, const int* __restrict__ ei) {
    int p = blockIdx.x * 256 + threadIdx.x;
    if (p < Ee) csr[p] = ei[csr[p]];
}

// ================= f32 -> bf16 bulk convert =================
__global__ void k_cvt(const float* __restrict__ x, short* __restrict__ xb, int total8) {
    int i = blockIdx.x * 256 + threadIdx.x;
    if (i >= total8) return;
    float4 a = *(const float4*)(x + (size_t)i * 8);
    float4 b = *(const float4*)(x + (size_t)i * 8 + 4);
    short8 h;
    h[0] = f2bf(a.x); h[1] = f2bf(a.y); h[2] = f2bf(a.z); h[3] = f2bf(a.w);
    h[4] = f2bf(b.x); h[5] = f2bf(b.y); h[6] = f2bf(b.z); h[7] = f2bf(b.w);
    *(short8*)(xb + (size_t)i * 8) = h;
}

// ================= EA slice of A (layer-invariant): [2*CIN .. 2*CIN+16) + zero pad =================
template<int CIN, int KP>
__global__ void k_ea_init(const float* __restrict__ easum, short* __restrict__ A) {
    int n = blockIdx.x * 256 + threadIdx.x;
    if (n >= Nn) return;
    const float* e = easum + (size_t)n * ECc;
    short* Ar = A + (size_t)n * KP + 2 * CIN;
    short8 h;
    #pragma unroll
    for (int i = 0; i < 8; ++i) h[i] = f2bf(e[i]);
    *(short8*)(Ar) = h;
    #pragma unroll
    for (int i = 0; i < 8; ++i) h[i] = f2bf(e[8 + i]);
    *(short8*)(Ar + 8) = h;
    short8 z = (short8){0, 0, 0, 0, 0, 0, 0, 0};
    *(short8*)(Ar + 16) = z;
    *(short8*)(Ar + 24) = z;           // pad to KP (KP - 2*CIN == 32 shorts total incl EA)
}

// ================= weight transpose + bf16 =================
__global__ void k_tbf(const float* __restrict__ W, short* __restrict__ WT,
                      int K, int Ncols, int KP) {
    int idx = blockIdx.x * 256 + threadIdx.x;
    int c = idx / KP, k = idx % KP;
    if (c >= Ncols) return;
    WT[(size_t)c * KP + k] = (k < K) ? f2bf(W[(size_t)k * Ncols + c]) : (short)0;
}

// ================= gather (bf16) + A self/neighbor slots =================
template<int CIN, int KP>
__global__ __launch_bounds__(256) void k_gather_prep(
    const int* __restrict__ rowptr, const int* __restrict__ csr,
    const short* __restrict__ xb, const float* __restrict__ deg,
    short* __restrict__ A)
{
    constexpr int TPN = CIN / 8;
    int idx = blockIdx.x * 256 + threadIdx.x;
    int n = idx / TPN, q = idx % TPN;
    if (n >= Nn) return;
    int beg = rowptr[n], end = rowptr[n + 1];
    float acc[8] = {0.f, 0.f, 0.f, 0.f, 0.f, 0.f, 0.f, 0.f};
    int p = beg;
    for (; p + 1 < end; p += 2) {
        int s0 = csr[p], s1 = csr[p + 1];
        short8 v0 = *(const short8*)(xb + (size_t)s0 * CIN + q * 8);
        short8 v1 = *(const short8*)(xb + (size_t)s1 * CIN + q * 8);
        #pragma unroll
        for (int i = 0; i < 8; ++i) acc[i] += bf2f(v0[i]) + bf2f(v1[i]);
    }
    if (p < end) {
        int s0 = csr[p];
        short8 v0 = *(const short8*)(xb + (size_t)s0 * CIN + q * 8);
        #pragma unroll
        for (int i = 0; i < 8; ++i) acc[i] += bf2f(v0[i]);
    }
    short8 xv = *(const short8*)(xb + (size_t)n * CIN + q * 8);
    float dg = deg[n];
    short8 h0, h1;
    #pragma unroll
    for (int i = 0; i < 8; ++i) {
        float xf = bf2f(xv[i]);
        h0[i] = f2bf(dg * xf);
        h1[i] = f2bf(acc[i] + xf);
    }
    short* Ar = A + (size_t)n * KP;
    *(short8*)(Ar + q * 8) = h0;
    *(short8*)(Ar + CIN + q * 8) = h1;
}

// ================= layer GEMM (MFMA, LDS-free) -> bf16 x out =================
template<int KP>
__global__ __launch_bounds__(256) void k_layer_mfma(
    const short* __restrict__ A, const short* __restrict__ WT,
    const float* __restrict__ deg, const float* __restrict__ bias,
    const float* __restrict__ gamma, const float* __restrict__ beta,
    const float* __restrict__ rmean, const float* __restrict__ rvar,
    short* __restrict__ xoutb)
{
    const int wv = threadIdx.x >> 6, lane = threadIdx.x & 63;
    const int lr = lane & 15, lk = lane >> 4;
    const int row0 = blockIdx.x * 128 + wv * 32;
    const short* Ap0 = A + (size_t)(row0 + lr) * KP + lk * 8;
    const short* Ap1 = Ap0 + (size_t)16 * KP;
    const short* Bp  = WT + (size_t)lr * KP + lk * 8;

    f32x4 acc[2][8];
    #pragma unroll
    for (int i = 0; i < 2; ++i)
        #pragma unroll
        for (int j = 0; j < 8; ++j) acc[i][j] = (f32x4){0.f, 0.f, 0.f, 0.f};

    #pragma unroll 2
    for (int k0 = 0; k0 < KP; k0 += 32) {
        short8 a0 = *(const short8*)(Ap0 + k0);
        short8 a1 = *(const short8*)(Ap1 + k0);
        #pragma unroll
        for (int j = 0; j < 8; ++j) {
            short8 b = *(const short8*)(Bp + (size_t)j * 16 * KP + k0);
            acc[0][j] = __builtin_amdgcn_mfma_f32_16x16x32_bf16(a0, b, acc[0][j], 0, 0, 0);
            acc[1][j] = __builtin_amdgcn_mfma_f32_16x16x32_bf16(a1, b, acc[1][j], 0, 0, 0);
        }
    }

    #pragma unroll
    for (int rf = 0; rf < 2; ++rf) {
        int rbase = row0 + rf * 16 + lk * 4;
        float dgs[4];
        #pragma unroll
        for (int i = 0; i < 4; ++i)
            dgs[i] = (rbase + i < Nn) ? deg[rbase + i] : 0.f;
        #pragma unroll
        for (int j = 0; j < 8; ++j) {
            int c = j * 16 + lr;
            float bb = bias[c], gm = gamma[c], bt = beta[c], rm = rmean[c];
            float inv = rsqrtf(rvar[c] + 1e-5f);
            #pragma unroll
            for (int i = 0; i < 4; ++i) {
                int r = rbase + i;
                if (r < Nn) {
                    float v = frelu(acc[rf][j][i] + dgs[i] * bb);
                    v = frelu((v - rm) * inv * gm + bt);
                    xoutb[(size_t)r * HC + c] = f2bf(v);
                }
            }
        }
    }
}

// ================= pooling (bf16 x, run-segmented) =================
__global__ void k_pool2(const short* __restrict__ xbf, const int* __restrict__ batch,
                        float* __restrict__ pooled) {
    constexpr int NPG = 64;
    int gid  = (blockIdx.x * 256 + threadIdx.x) >> 5;
    int lane = threadIdx.x & 31;
    int n0 = gid * NPG;
    if (n0 >= Nn) return;
    int nend = min(n0 + NPG, Nn);
    int curg = batch[n0];
    float4 acc = make_float4(0.f, 0.f, 0.f, 0.f);
    for (int n = n0; n < nend; ++n) {
        int g = batch[n];
        if (g != curg) {
            float* p = pooled + (size_t)curg * HC + lane * 4;
            atomicAdd(p + 0, acc.x); atomicAdd(p + 1, acc.y);
            atomicAdd(p + 2, acc.z); atomicAdd(p + 3, acc.w);
            acc = make_float4(0.f, 0.f, 0.f, 0.f);
            curg = g;
        }
        short4v v = *(const short4v*)(xbf + (size_t)n * HC + lane * 4);
        acc.x += bf2f(v[0]); acc.y += bf2f(v[1]);
        acc.z += bf2f(v[2]); acc.w += bf2f(v[3]);
    }
    float* p = pooled + (size_t)curg * HC + lane * 4;
    atomicAdd(p + 0, acc.x); atomicAdd(p + 1, acc.y);
    atomicAdd(p + 2, acc.z); atomicAdd(p + 3, acc.w);
}

// ================= Prow = pooled @ fc1_w[128:,:] + fc1_b (f32) =================
__global__ void k_prow(const float* __restrict__ pooled, const float* __restrict__ fc1w,
                       const float* __restrict__ fc1b, float* __restrict__ prow) {
    int g = blockIdx.x;
    int j = threadIdx.x;
    __shared__ float ps[HC];
    if (j < HC) ps[j] = pooled[(size_t)g * HC + j];
    __syncthreads();
    float v = fc1b[j];
    #pragma unroll 4
    for (int k = 0; k < HC; ++k)
        v += ps[k] * fc1w[(size_t)(HC + k) * MLPc + j];
    prow[(size_t)g * MLPc + j] = v;
}

// ================= fused fc1+fc2 (MFMA) =================
__global__ __launch_bounds__(256) void k_fc_mfma(
    const short* __restrict__ xbf, const float* __restrict__ prow,
    const int* __restrict__ batch, const short* __restrict__ fc1wT,  // [256][128]
    const short* __restrict__ fc2wT,                                  // [32][256]
    const float* __restrict__ fc2b, float* __restrict__ out)
{
    __shared__ short h1s[64][264];
    const int wv = threadIdx.x >> 6, lane = threadIdx.x & 63;
    const int lr = lane & 15, lk = lane >> 4;
    const int row0 = blockIdx.x * 64;
    const int rw = row0 + wv * 16;

    f32x4 acc[16];
    #pragma unroll
    for (int j = 0; j < 16; ++j) acc[j] = (f32x4){0.f, 0.f, 0.f, 0.f};
    const short* Ap = xbf + (size_t)(rw + lr) * HC + lk * 8;
    #pragma unroll 2
    for (int k0 = 0; k0 < 128; k0 += 32) {
        short8 a = *(const short8*)(Ap + k0);
        #pragma unroll
        for (int j = 0; j < 16; ++j) {
            short8 b = *(const short8*)(fc1wT + (size_t)(j * 16 + lr) * 128 + k0 + lk * 8);
            acc[j] = __builtin_amdgcn_mfma_f32_16x16x32_bf16(a, b, acc[j], 0, 0, 0);
        }
    }
    int rbase = rw + lk * 4;
    int gg[4];
    #pragma unroll
    for (int i = 0; i < 4; ++i)
        gg[i] = (rbase + i < Nn) ? batch[rbase + i] : 0;
    #pragma unroll
    for (int j = 0; j < 16; ++j) {
        int c = j * 16 + lr;
        #pragma unroll
        for (int i = 0; i < 4; ++i) {
            float pv = prow[(size_t)gg[i] * MLPc + c];
            h1s[rbase - row0 + i][c] = f2bf(frelu(acc[j][i] + pv));
        }
    }
    __syncthreads();

    f32x4 acc2[2];
    acc2[0] = (f32x4){0.f, 0.f, 0.f, 0.f};
    acc2[1] = (f32x4){0.f, 0.f, 0.f, 0.f};
    #pragma unroll 2
    for (int k0 = 0; k0 < 256; k0 += 32) {
        short8 a = *(const short8*)(&h1s[wv * 16 + lr][k0 + lk * 8]);
        #pragma unroll
        for (int cf = 0; cf < 2; ++cf) {
            short8 b = *(const short8*)(fc2wT + (size_t)(cf * 16 + lr) * 256 + k0 + lk * 8);
            acc2[cf] = __builtin_amdgcn_mfma_f32_16x16x32_bf16(a, b, acc2[cf], 0, 0, 0);
        }
    }
    #pragma unroll
    for (int cf = 0; cf < 2; ++cf) {
        int c = cf * 16 + lr;
        float bb = fc2b[c];
        #pragma unroll
        for (int i = 0; i < 4; ++i) {
            int r = rbase + i;
            if (r < Nn) out[(size_t)r * NCc + c] = acc2[cf][i] + bb;
        }
    }
}

// ================= launch =================
extern "C" void kernel_launch(void* const* d_in, const int* in_sizes, int n_in,
                              void* d_out, int out_size, void* d_ws, size_t ws_size,
                              hipStream_t stream) {
    const float* x_in  = (const float*)d_in[0];
    const int*   ei    = (const int*)d_in[1];
    const float* ea    = (const float*)d_in[2];
    const int*   batch = (const int*)d_in[3];
    const float* W0 = (const float*)d_in[4];
    const float* b0 = (const float*)d_in[5];
    const float* g0 = (const float*)d_in[6];
    const float* be0 = (const float*)d_in[7];
    const float* rm0 = (const float*)d_in[8];
    const float* rv0 = (const float*)d_in[9];
    const float* W1 = (const float*)d_in[10];
    const float* b1 = (const float*)d_in[11];
    const float* g1 = (const float*)d_in[12];
    const float* be1 = (const float*)d_in[13];
    const float* rm1 = (const float*)d_in[14];
    const float* rv1 = (const float*)d_in[15];
    const float* W2 = (const float*)d_in[16];
    const float* b2 = (const float*)d_in[17];
    const float* g2 = (const float*)d_in[18];
    const float* be2 = (const float*)d_in[19];
    const float* rm2 = (const float*)d_in[20];
    const float* rv2 = (const float*)d_in[21];
    const float* fc1w = (const float*)d_in[22];
    const float* fc1b = (const float*)d_in[23];
    const float* fc2w = (const float*)d_in[24];
    const float* fc2b = (const float*)d_in[25];

    size_t off = 0;
    auto alloc = [&](size_t bytes) {
        void* p = (char*)d_ws + off;
        off += (bytes + 255) & ~(size_t)255;
        return p;
    };
    int*   rowptr   = (int*)alloc((size_t)(Nn + 1) * 4);
    int*   partials = (int*)alloc(256 * 4);
    float* easum    = (float*)alloc((size_t)Nn * ECc * 4);
    float* deg      = (float*)alloc((size_t)Nn * 4);
    int*   degi     = (int*)alloc((size_t)Nn * 4);
    int*   cursor   = (int*)alloc((size_t)Nn * 4);
    short* xb0      = (short*)alloc((size_t)Nn * INC * 2);        // bf16 input
    short* xbA      = (short*)alloc((size_t)Nn * HC * 2);         // x1, then x2
    short* xb3      = (short*)alloc((size_t)Mpad * HC * 2);       // layer-2 out
    short* A0       = (short*)alloc((size_t)Mpad * 160 * 2);
    short* A12      = (short*)alloc((size_t)Mpad * 288 * 2);
    short* WT0      = (short*)alloc((size_t)HC * 160 * 2);
    short* WT1      = (short*)alloc((size_t)HC * 288 * 2);
    short* WT2      = (short*)alloc((size_t)HC * 288 * 2);
    short* fc1wT    = (short*)alloc((size_t)MLPc * 128 * 2);
    short* fc2wT    = (short*)alloc((size_t)NCc * 256 * 2);
    float* pooled   = (float*)alloc((size_t)Gg * HC * 4);
    float* prow     = (float*)alloc((size_t)Gg * MLPc * 4);

    int* csr = (int*)d_out;   // 3.2MB in 6.4MB d_out; dead before k_fc writes out

    constexpr int NB = (Nn + 255) / 256;

    // ---- CSR build ----
    hipMemsetAsync(degi, 0, (size_t)Nn * 4, stream);
    k_count<<<(Ee + 255) / 256, 256, 0, stream>>>(ei, degi);
    k_scan_block<<<NB, 256, 0, stream>>>(degi, rowptr, partials, Nn);
    k_scan_block<<<1, 256, 0, stream>>>(partials, partials, nullptr, NB);
    k_scan_add<<<NB, 256, 0, stream>>>(rowptr, partials);
    k_cursor_deg<<<NB, 256, 0, stream>>>(rowptr, cursor, deg);
    k_fill<<<(Ee + 255) / 256, 256, 0, stream>>>(ei, cursor, csr);
    k_ea_gather<<<(Nn * 4 + 255) / 256, 256, 0, stream>>>(rowptr, csr, ea, easum);
    k_convert<<<(Ee + 255) / 256, 256, 0, stream>>>(csr, ei);

    // ---- one-time prep: bf16 input, EA slices, bf16 weights ----
    k_cvt<<<(Nn * INC / 8 + 255) / 256, 256, 0, stream>>>(x_in, xb0, Nn * INC / 8);
    k_ea_init<INC, 160><<<NB, 256, 0, stream>>>(easum, A0);
    k_ea_init<HC, 288><<<NB, 256, 0, stream>>>(easum, A12);
    k_tbf<<<(HC * 160 + 255) / 256, 256, 0, stream>>>(W0, WT0, 144, HC, 160);
    k_tbf<<<(HC * 288 + 255) / 256, 256, 0, stream>>>(W1, WT1, 272, HC, 288);
    k_tbf<<<(HC * 288 + 255) / 256, 256, 0, stream>>>(W2, WT2, 272, HC, 288);
    k_tbf<<<(MLPc * 128 + 255) / 256, 256, 0, stream>>>(fc1w, fc1wT, 128, MLPc, 128);
    k_tbf<<<(NCc * 256 + 255) / 256, 256, 0, stream>>>(fc2w, fc2wT, 256, NCc, 256);

    const int LGRID = (Mpad + 127) / 128;   // 391

    // ---- layer 0 ----
    k_gather_prep<INC, 160><<<(Nn * (INC / 8) + 255) / 256, 256, 0, stream>>>(
        rowptr, csr, xb0, deg, A0);
    k_layer_mfma<160><<<LGRID, 256, 0, stream>>>(A0, WT0, deg,
        b0, g0, be0, rm0, rv0, xbA);

    // ---- layer 1 ----
    k_gather_prep<HC, 288><<<(Nn * (HC / 8) + 255) / 256, 256, 0, stream>>>(
        rowptr, csr, xbA, deg, A12);
    k_layer_mfma<288><<<LGRID, 256, 0, stream>>>(A12, WT1, deg,
        b1, g1, be1, rm1, rv1, xbA);

    // ---- layer 2 ----
    k_gather_prep<HC, 288><<<(Nn * (HC / 8) + 255) / 256, 256, 0, stream>>>(
        rowptr, csr, xbA, deg, A12);
    k_layer_mfma<288><<<LGRID, 256, 0, stream>>>(A12, WT2, deg,
        b2, g2, be2, rm2, rv2, xb3);

    // ---- pool + Prow ----
    hipMemsetAsync(pooled, 0, (size_t)Gg * HC * 4, stream);
    k_pool2<<<((Nn + 63) / 64 * 32 + 255) / 256, 256, 0, stream>>>(xb3, batch, pooled);
    k_prow<<<Gg, 256, 0, stream>>>(pooled, fc1w, fc1b, prow);

    // ---- fused fc1 + fc2 ----
    k_fc_mfma<<<(Mpad + 63) / 64, 256, 0, stream>>>(xb3, prow, batch, fc1wT, fc2wT,
                                                    fc2b, (float*)d_out);
}

// Round 5
// 322.904 us; speedup vs baseline: 12.8924x; 1.2492x over previous
//
#include <hip/hip_runtime.h>

constexpr int Nn   = 50000;
constexpr int Ee   = 800000;
constexpr int INC  = 64;
constexpr int HC   = 128;
constexpr int ECc  = 16;
constexpr int MLPc = 256;
constexpr int NCc  = 32;
constexpr int Gg   = 512;
constexpr int Mpad = 50048;          // 391*128

typedef __attribute__((ext_vector_type(8))) short short8;
typedef __attribute__((ext_vector_type(4))) short short4v;
typedef __attribute__((ext_vector_type(4))) float f32x4;

__device__ __forceinline__ float frelu(float v) { return v > 0.f ? v : 0.f; }

__device__ __forceinline__ short f2bf(float f) {
    unsigned u = __float_as_uint(f);
    unsigned r = (u + 0x7fffu + ((u >> 16) & 1u)) >> 16;
    return (short)r;
}
__device__ __forceinline__ float bf2f(short s) {
    return __uint_as_float(((unsigned)(unsigned short)s) << 16);
}

// ================= CSR build (single atomic pass) =================
__global__ void k_rank(const int* __restrict__ ei, int* __restrict__ degi,
                       int* __restrict__ rank) {
    int e = blockIdx.x * 256 + threadIdx.x;
    if (e < Ee) rank[e] = atomicAdd(&degi[ei[Ee + e]], 1);
}

__global__ void k_scan_block(const int* __restrict__ in, int* __restrict__ out,
                             int* __restrict__ partials, int n) {
    __shared__ int s[256];
    int i = blockIdx.x * 256 + threadIdx.x;
    int v = (i < n) ? in[i] : 0;
    s[threadIdx.x] = v;
    __syncthreads();
    #pragma unroll
    for (int off = 1; off < 256; off <<= 1) {
        int t = (threadIdx.x >= off) ? s[threadIdx.x - off] : 0;
        __syncthreads();
        s[threadIdx.x] += t;
        __syncthreads();
    }
    if (i < n) out[i] = s[threadIdx.x] - v;
    if (partials && threadIdx.x == 255) partials[blockIdx.x] = s[255];
}

__global__ void k_scan_add(int* __restrict__ rowptr, const int* __restrict__ partials,
                           const int* __restrict__ degi, float* __restrict__ deg) {
    int i = blockIdx.x * 256 + threadIdx.x;
    if (i < Nn) {
        rowptr[i] += partials[blockIdx.x];
        deg[i] = (float)(degi[i] + 1);       // +1 self loop
    }
    if (i == 0) rowptr[Nn] = Ee;
}

// atomic-free bucket placement
__global__ void k_fill2(const int* __restrict__ ei, const int* __restrict__ rowptr,
                        const int* __restrict__ rank, int* __restrict__ csr) {
    int e = blockIdx.x * 256 + threadIdx.x;
    if (e >= Ee) return;
    int d = ei[Ee + e];
    csr[rowptr[d] + rank[e]] = e;
}

// easum (bf16, [EA(16)|zeros(16)] per row) + in-place csr edgeid->src conversion
__global__ void k_eaconv(const int* __restrict__ rowptr, int* __restrict__ csr,
                         const int* __restrict__ ei, const float* __restrict__ ea,
                         short* __restrict__ eab) {
    int idx = blockIdx.x * 256 + threadIdx.x;
    int n = idx >> 2, q = idx & 3;
    if (n >= Nn) return;
    int beg = rowptr[n], end = rowptr[n + 1];
    float4 acc = make_float4(1.f, 1.f, 1.f, 1.f);   // self-loop fill=1.0
    for (int p = beg; p < end; ++p) {
        int e = csr[p];
        float4 v = *(const float4*)(ea + (size_t)e * ECc + q * 4);
        acc.x += v.x; acc.y += v.y; acc.z += v.z; acc.w += v.w;
    }
    short4v h;
    h[0] = f2bf(acc.x); h[1] = f2bf(acc.y); h[2] = f2bf(acc.z); h[3] = f2bf(acc.w);
    *(short4v*)(eab + (size_t)n * 32 + q * 4) = h;
    short4v z; z[0] = 0; z[1] = 0; z[2] = 0; z[3] = 0;
    *(short4v*)(eab + (size_t)n * 32 + 16 + q * 4) = z;
    // convert own segment (same wave as the readers above -> no race)
    for (int p = beg + q; p < end; p += 4)
        csr[p] = ei[csr[p]];
}

// ================= one-shot prep: 5 weight transposes + x_in -> bf16 =================
__device__ __forceinline__ void tbf_one(const float* __restrict__ W, short* __restrict__ WT,
                                        int K, int Ncols, int KP, int idx) {
    int c = idx / KP, k = idx % KP;
    WT[(size_t)c * KP + k] = (k < K) ? f2bf(W[(size_t)k * Ncols + c]) : (short)0;
}

__global__ void k_prep(const float* __restrict__ W0, const float* __restrict__ W1,
                       const float* __restrict__ W2, const float* __restrict__ fc1w,
                       const float* __restrict__ fc2w, const float* __restrict__ x_in,
                       short* __restrict__ WT0, short* __restrict__ WT1,
                       short* __restrict__ WT2, short* __restrict__ fc1wT,
                       short* __restrict__ fc2wT, short* __restrict__ xb0) {
    int idx = blockIdx.x * 256 + threadIdx.x;
    if (idx < 20480) { tbf_one(W0, WT0, 144, 128, 160, idx); return; }
    idx -= 20480;
    if (idx < 36864) { tbf_one(W1, WT1, 272, 128, 288, idx); return; }
    idx -= 36864;
    if (idx < 36864) { tbf_one(W2, WT2, 272, 128, 288, idx); return; }
    idx -= 36864;
    if (idx < 32768) { tbf_one(fc1w, fc1wT, 128, 256, 128, idx); return; }
    idx -= 32768;
    if (idx < 8192) { tbf_one(fc2w, fc2wT, 256, 32, 256, idx); return; }
    idx -= 8192;
    if (idx < 400000) {
        float4 a = *(const float4*)(x_in + (size_t)idx * 8);
        float4 b = *(const float4*)(x_in + (size_t)idx * 8 + 4);
        short8 h;
        h[0] = f2bf(a.x); h[1] = f2bf(a.y); h[2] = f2bf(a.z); h[3] = f2bf(a.w);
        h[4] = f2bf(b.x); h[5] = f2bf(b.y); h[6] = f2bf(b.z); h[7] = f2bf(b.w);
        *(short8*)(xb0 + (size_t)idx * 8) = h;
    }
}

// ================= neighbor gather: G[n] = bf16( sum x[src] + x[n] ) =================
template<int CIN>
__global__ __launch_bounds__(256) void k_gather(
    const int* __restrict__ rowptr, const int* __restrict__ csr,
    const short* __restrict__ xb, short* __restrict__ G)
{
    constexpr int TPN = CIN / 8;
    int idx = blockIdx.x * 256 + threadIdx.x;
    int n = idx / TPN, q = idx % TPN;
    if (n >= Nn) return;
    int beg = rowptr[n], end = rowptr[n + 1];
    float acc[8] = {0.f, 0.f, 0.f, 0.f, 0.f, 0.f, 0.f, 0.f};
    int p = beg;
    for (; p + 1 < end; p += 2) {
        int s0 = csr[p], s1 = csr[p + 1];
        short8 v0 = *(const short8*)(xb + (size_t)s0 * CIN + q * 8);
        short8 v1 = *(const short8*)(xb + (size_t)s1 * CIN + q * 8);
        #pragma unroll
        for (int i = 0; i < 8; ++i) acc[i] += bf2f(v0[i]) + bf2f(v1[i]);
    }
    if (p < end) {
        int s0 = csr[p];
        short8 v0 = *(const short8*)(xb + (size_t)s0 * CIN + q * 8);
        #pragma unroll
        for (int i = 0; i < 8; ++i) acc[i] += bf2f(v0[i]);
    }
    short8 xv = *(const short8*)(xb + (size_t)n * CIN + q * 8);
    short8 h;
    #pragma unroll
    for (int i = 0; i < 8; ++i) h[i] = f2bf(acc[i] + bf2f(xv[i]));
    *(short8*)(G + (size_t)n * CIN + q * 8) = h;
}

// ================= split-GEMM layer: acc = deg.(x@Ws) + G@Wn + EA@We; BN/relu =================
template<int CIN>
__global__ __launch_bounds__(256) void k_layer_mfma(
    const short* __restrict__ xs, const short* __restrict__ G,
    const short* __restrict__ eab, const short* __restrict__ WT,
    const float* __restrict__ deg, const float* __restrict__ bias,
    const float* __restrict__ gamma, const float* __restrict__ beta,
    const float* __restrict__ rmean, const float* __restrict__ rvar,
    short* __restrict__ xoutb)
{
    constexpr int KP = 2 * CIN + 32;
    const int wv = threadIdx.x >> 6, lane = threadIdx.x & 63;
    const int lr = lane & 15, lk = lane >> 4;
    const int row0 = blockIdx.x * 128 + wv * 32;
    const short* Xp0 = xs + (size_t)(row0 + lr) * CIN + lk * 8;
    const short* Xp1 = Xp0 + (size_t)16 * CIN;
    const short* Gp0 = G + (size_t)(row0 + lr) * CIN + lk * 8;
    const short* Gp1 = Gp0 + (size_t)16 * CIN;
    const short* Bp  = WT + (size_t)lr * KP + lk * 8;

    f32x4 acc[2][8];
    #pragma unroll
    for (int i = 0; i < 2; ++i)
        #pragma unroll
        for (int j = 0; j < 8; ++j) acc[i][j] = (f32x4){0.f, 0.f, 0.f, 0.f};

    // phase 1: self  x @ Wself  (WT k in [0,CIN))
    #pragma unroll
    for (int k0 = 0; k0 < CIN; k0 += 32) {
        short8 a0 = *(const short8*)(Xp0 + k0);
        short8 a1 = *(const short8*)(Xp1 + k0);
        #pragma unroll
        for (int j = 0; j < 8; ++j) {
            short8 b = *(const short8*)(Bp + (size_t)j * 16 * KP + k0);
            acc[0][j] = __builtin_amdgcn_mfma_f32_16x16x32_bf16(a0, b, acc[0][j], 0, 0, 0);
            acc[1][j] = __builtin_amdgcn_mfma_f32_16x16x32_bf16(a1, b, acc[1][j], 0, 0, 0);
        }
    }
    // per-row deg scale (exact: deg*(x@W) == (deg*x)@W)
    float dgs[2][4];
    #pragma unroll
    for (int rf = 0; rf < 2; ++rf) {
        int rbase = row0 + rf * 16 + lk * 4;
        #pragma unroll
        for (int i = 0; i < 4; ++i)
            dgs[rf][i] = (rbase + i < Nn) ? deg[rbase + i] : 0.f;
    }
    #pragma unroll
    for (int rf = 0; rf < 2; ++rf)
        #pragma unroll
        for (int j = 0; j < 8; ++j)
            #pragma unroll
            for (int i = 0; i < 4; ++i) acc[rf][j][i] *= dgs[rf][i];

    // phase 2: neighbor  G @ Wnbr  (WT k in [CIN,2CIN))
    #pragma unroll
    for (int k0 = 0; k0 < CIN; k0 += 32) {
        short8 a0 = *(const short8*)(Gp0 + k0);
        short8 a1 = *(const short8*)(Gp1 + k0);
        #pragma unroll
        for (int j = 0; j < 8; ++j) {
            short8 b = *(const short8*)(Bp + (size_t)j * 16 * KP + CIN + k0);
            acc[0][j] = __builtin_amdgcn_mfma_f32_16x16x32_bf16(a0, b, acc[0][j], 0, 0, 0);
            acc[1][j] = __builtin_amdgcn_mfma_f32_16x16x32_bf16(a1, b, acc[1][j], 0, 0, 0);
        }
    }
    // phase 3: EA @ Wea  (WT k in [2CIN, 2CIN+32), eab row = [EA|zeros])
    {
        short8 e0 = *(const short8*)(eab + (size_t)(row0 + lr) * 32 + lk * 8);
        short8 e1 = *(const short8*)(eab + (size_t)(row0 + 16 + lr) * 32 + lk * 8);
        #pragma unroll
        for (int j = 0; j < 8; ++j) {
            short8 b = *(const short8*)(Bp + (size_t)j * 16 * KP + 2 * CIN);
            acc[0][j] = __builtin_amdgcn_mfma_f32_16x16x32_bf16(e0, b, acc[0][j], 0, 0, 0);
            acc[1][j] = __builtin_amdgcn_mfma_f32_16x16x32_bf16(e1, b, acc[1][j], 0, 0, 0);
        }
    }

    #pragma unroll
    for (int rf = 0; rf < 2; ++rf) {
        int rbase = row0 + rf * 16 + lk * 4;
        #pragma unroll
        for (int j = 0; j < 8; ++j) {
            int c = j * 16 + lr;
            float bb = bias[c], gm = gamma[c], bt = beta[c], rm = rmean[c];
            float inv = rsqrtf(rvar[c] + 1e-5f);
            #pragma unroll
            for (int i = 0; i < 4; ++i) {
                int r = rbase + i;
                if (r < Nn) {
                    float v = frelu(acc[rf][j][i] + dgs[rf][i] * bb);
                    v = frelu((v - rm) * inv * gm + bt);
                    xoutb[(size_t)r * HC + c] = f2bf(v);
                }
            }
        }
    }
}

// ================= pooling (bf16 x, run-segmented) =================
__global__ void k_pool2(const short* __restrict__ xbf, const int* __restrict__ batch,
                        float* __restrict__ pooled) {
    constexpr int NPG = 64;
    int gid  = (blockIdx.x * 256 + threadIdx.x) >> 5;
    int lane = threadIdx.x & 31;
    int n0 = gid * NPG;
    if (n0 >= Nn) return;
    int nend = min(n0 + NPG, Nn);
    int curg = batch[n0];
    float4 acc = make_float4(0.f, 0.f, 0.f, 0.f);
    for (int n = n0; n < nend; ++n) {
        int g = batch[n];
        if (g != curg) {
            float* p = pooled + (size_t)curg * HC + lane * 4;
            atomicAdd(p + 0, acc.x); atomicAdd(p + 1, acc.y);
            atomicAdd(p + 2, acc.z); atomicAdd(p + 3, acc.w);
            acc = make_float4(0.f, 0.f, 0.f, 0.f);
            curg = g;
        }
        short4v v = *(const short4v*)(xbf + (size_t)n * HC + lane * 4);
        acc.x += bf2f(v[0]); acc.y += bf2f(v[1]);
        acc.z += bf2f(v[2]); acc.w += bf2f(v[3]);
    }
    float* p = pooled + (size_t)curg * HC + lane * 4;
    atomicAdd(p + 0, acc.x); atomicAdd(p + 1, acc.y);
    atomicAdd(p + 2, acc.z); atomicAdd(p + 3, acc.w);
}

// ================= Prow = pooled @ fc1_w[128:,:] + fc1_b (f32) =================
__global__ void k_prow(const float* __restrict__ pooled, const float* __restrict__ fc1w,
                       const float* __restrict__ fc1b, float* __restrict__ prow) {
    int g = blockIdx.x;
    int j = threadIdx.x;
    __shared__ float ps[HC];
    if (j < HC) ps[j] = pooled[(size_t)g * HC + j];
    __syncthreads();
    float v = fc1b[j];
    #pragma unroll 4
    for (int k = 0; k < HC; ++k)
        v += ps[k] * fc1w[(size_t)(HC + k) * MLPc + j];
    prow[(size_t)g * MLPc + j] = v;
}

// ================= fused fc1+fc2 (MFMA) =================
__global__ __launch_bounds__(256) void k_fc_mfma(
    const short* __restrict__ xbf, const float* __restrict__ prow,
    const int* __restrict__ batch, const short* __restrict__ fc1wT,  // [256][128]
    const short* __restrict__ fc2wT,                                  // [32][256]
    const float* __restrict__ fc2b, float* __restrict__ out)
{
    __shared__ short h1s[64][264];
    const int wv = threadIdx.x >> 6, lane = threadIdx.x & 63;
    const int lr = lane & 15, lk = lane >> 4;
    const int row0 = blockIdx.x * 64;
    const int rw = row0 + wv * 16;

    f32x4 acc[16];
    #pragma unroll
    for (int j = 0; j < 16; ++j) acc[j] = (f32x4){0.f, 0.f, 0.f, 0.f};
    const short* Ap = xbf + (size_t)(rw + lr) * HC + lk * 8;
    #pragma unroll 2
    for (int k0 = 0; k0 < 128; k0 += 32) {
        short8 a = *(const short8*)(Ap + k0);
        #pragma unroll
        for (int j = 0; j < 16; ++j) {
            short8 b = *(const short8*)(fc1wT + (size_t)(j * 16 + lr) * 128 + k0 + lk * 8);
            acc[j] = __builtin_amdgcn_mfma_f32_16x16x32_bf16(a, b, acc[j], 0, 0, 0);
        }
    }
    int rbase = rw + lk * 4;
    int gg[4];
    #pragma unroll
    for (int i = 0; i < 4; ++i)
        gg[i] = (rbase + i < Nn) ? batch[rbase + i] : 0;
    #pragma unroll
    for (int j = 0; j < 16; ++j) {
        int c = j * 16 + lr;
        #pragma unroll
        for (int i = 0; i < 4; ++i) {
            float pv = prow[(size_t)gg[i] * MLPc + c];
            h1s[rbase - row0 + i][c] = f2bf(frelu(acc[j][i] + pv));
        }
    }
    __syncthreads();

    f32x4 acc2[2];
    acc2[0] = (f32x4){0.f, 0.f, 0.f, 0.f};
    acc2[1] = (f32x4){0.f, 0.f, 0.f, 0.f};
    #pragma unroll 2
    for (int k0 = 0; k0 < 256; k0 += 32) {
        short8 a = *(const short8*)(&h1s[wv * 16 + lr][k0 + lk * 8]);
        #pragma unroll
        for (int cf = 0; cf < 2; ++cf) {
            short8 b = *(const short8*)(fc2wT + (size_t)(cf * 16 + lr) * 256 + k0 + lk * 8);
            acc2[cf] = __builtin_amdgcn_mfma_f32_16x16x32_bf16(a, b, acc2[cf], 0, 0, 0);
        }
    }
    #pragma unroll
    for (int cf = 0; cf < 2; ++cf) {
        int c = cf * 16 + lr;
        float bb = fc2b[c];
        #pragma unroll
        for (int i = 0; i < 4; ++i) {
            int r = rbase + i;
            if (r < Nn) out[(size_t)r * NCc + c] = acc2[cf][i] + bb;
        }
    }
}

// ================= launch =================
extern "C" void kernel_launch(void* const* d_in, const int* in_sizes, int n_in,
                              void* d_out, int out_size, void* d_ws, size_t ws_size,
                              hipStream_t stream) {
    const float* x_in  = (const float*)d_in[0];
    const int*   ei    = (const int*)d_in[1];
    const float* ea    = (const float*)d_in[2];
    const int*   batch = (const int*)d_in[3];
    const float* W0 = (const float*)d_in[4];
    const float* b0 = (const float*)d_in[5];
    const float* g0 = (const float*)d_in[6];
    const float* be0 = (const float*)d_in[7];
    const float* rm0 = (const float*)d_in[8];
    const float* rv0 = (const float*)d_in[9];
    const float* W1 = (const float*)d_in[10];
    const float* b1 = (const float*)d_in[11];
    const float* g1 = (const float*)d_in[12];
    const float* be1 = (const float*)d_in[13];
    const float* rm1 = (const float*)d_in[14];
    const float* rv1 = (const float*)d_in[15];
    const float* W2 = (const float*)d_in[16];
    const float* b2 = (const float*)d_in[17];
    const float* g2 = (const float*)d_in[18];
    const float* be2 = (const float*)d_in[19];
    const float* rm2 = (const float*)d_in[20];
    const float* rv2 = (const float*)d_in[21];
    const float* fc1w = (const float*)d_in[22];
    const float* fc1b = (const float*)d_in[23];
    const float* fc2w = (const float*)d_in[24];
    const float* fc2b = (const float*)d_in[25];

    size_t off = 0;
    auto alloc = [&](size_t bytes) {
        void* p = (char*)d_ws + off;
        off += (bytes + 255) & ~(size_t)255;
        return p;
    };
    int*   rowptr   = (int*)alloc((size_t)(Nn + 1) * 4);
    int*   partials = (int*)alloc(256 * 4);
    int*   rank     = (int*)alloc((size_t)Ee * 4);
    int*   degi     = (int*)alloc((size_t)Nn * 4);
    float* deg      = (float*)alloc((size_t)Nn * 4);
    short* eab      = (short*)alloc((size_t)Mpad * 32 * 2);
    short* xb0      = (short*)alloc((size_t)Mpad * INC * 2);
    short* xbA      = (short*)alloc((size_t)Mpad * HC * 2);
    short* xb3      = (short*)alloc((size_t)Mpad * HC * 2);
    short* G        = (short*)alloc((size_t)Mpad * HC * 2);
    short* WT0      = (short*)alloc((size_t)HC * 160 * 2);
    short* WT1      = (short*)alloc((size_t)HC * 288 * 2);
    short* WT2      = (short*)alloc((size_t)HC * 288 * 2);
    short* fc1wT    = (short*)alloc((size_t)MLPc * 128 * 2);
    short* fc2wT    = (short*)alloc((size_t)NCc * 256 * 2);
    float* pooled   = (float*)alloc((size_t)Gg * HC * 4);
    float* prow     = (float*)alloc((size_t)Gg * MLPc * 4);

    int* csr = (int*)d_out;   // 3.2MB in 6.4MB d_out; dead before k_fc writes out

    constexpr int NB = (Nn + 255) / 256;   // 196
    constexpr int EB = (Ee + 255) / 256;

    // ---- CSR build (one atomic pass) ----
    hipMemsetAsync(degi, 0, (size_t)Nn * 4, stream);
    k_rank<<<EB, 256, 0, stream>>>(ei, degi, rank);
    k_scan_block<<<NB, 256, 0, stream>>>(degi, rowptr, partials, Nn);
    k_scan_block<<<1, 256, 0, stream>>>(partials, partials, nullptr, NB);
    k_scan_add<<<NB, 256, 0, stream>>>(rowptr, partials, degi, deg);
    k_fill2<<<EB, 256, 0, stream>>>(ei, rowptr, rank, csr);
    k_eaconv<<<(Nn * 4 + 255) / 256, 256, 0, stream>>>(rowptr, csr, ei, ea, eab);

    // ---- one-shot prep: weights + input cvt ----
    k_prep<<<(535168 + 255) / 256, 256, 0, stream>>>(W0, W1, W2, fc1w, fc2w, x_in,
                                                     WT0, WT1, WT2, fc1wT, fc2wT, xb0);

    const int LGRID = (Mpad + 127) / 128;   // 391

    // ---- layer 0: xb0 -> xbA ----
    k_gather<INC><<<(Nn * (INC / 8) + 255) / 256, 256, 0, stream>>>(rowptr, csr, xb0, G);
    k_layer_mfma<INC><<<LGRID, 256, 0, stream>>>(xb0, G, eab, WT0, deg,
        b0, g0, be0, rm0, rv0, xbA);

    // ---- layer 1: xbA -> xbA (in-place safe: row-partitioned reads) ----
    k_gather<HC><<<(Nn * (HC / 8) + 255) / 256, 256, 0, stream>>>(rowptr, csr, xbA, G);
    k_layer_mfma<HC><<<LGRID, 256, 0, stream>>>(xbA, G, eab, WT1, deg,
        b1, g1, be1, rm1, rv1, xbA);

    // ---- layer 2: xbA -> xb3 ----
    k_gather<HC><<<(Nn * (HC / 8) + 255) / 256, 256, 0, stream>>>(rowptr, csr, xbA, G);
    k_layer_mfma<HC><<<LGRID, 256, 0, stream>>>(xbA, G, eab, WT2, deg,
        b2, g2, be2, rm2, rv2, xb3);

    // ---- pool + Prow ----
    hipMemsetAsync(pooled, 0, (size_t)Gg * HC * 4, stream);
    k_pool2<<<((Nn + 63) / 64 * 32 + 255) / 256, 256, 0, stream>>>(xb3, batch, pooled);
    k_prow<<<Gg, 256, 0, stream>>>(pooled, fc1w, fc1b, prow);

    // ---- fused fc1 + fc2 ----
    k_fc_mfma<<<(Mpad + 63) / 64, 256, 0, stream>>>(xb3, prow, batch, fc1wT, fc2wT,
                                                    fc2b, (float*)d_out);
}

// Round 6
// 301.808 us; speedup vs baseline: 13.7935x; 1.0699x over previous
//
#include <hip/hip_runtime.h>

constexpr int Nn   = 50000;
constexpr int Ee   = 800000;
constexpr int INC  = 64;
constexpr int HC   = 128;
constexpr int ECc  = 16;
constexpr int MLPc = 256;
constexpr int NCc  = 32;
constexpr int Gg   = 512;
constexpr int Mpad = 50048;          // 391*128

typedef __attribute__((ext_vector_type(8))) short short8;
typedef __attribute__((ext_vector_type(4))) short short4v;
typedef __attribute__((ext_vector_type(4))) float f32x4;

__device__ __forceinline__ float frelu(float v) { return v > 0.f ? v : 0.f; }

__device__ __forceinline__ short f2bf(float f) {
    unsigned u = __float_as_uint(f);
    unsigned r = (u + 0x7fffu + ((u >> 16) & 1u)) >> 16;
    return (short)r;
}
__device__ __forceinline__ float bf2f(short s) {
    return __uint_as_float(((unsigned)(unsigned short)s) << 16);
}

// ================= CSR build (single atomic pass) =================
__global__ void k_rank(const int* __restrict__ ei, int* __restrict__ degi,
                       int* __restrict__ rank) {
    int e = blockIdx.x * 256 + threadIdx.x;
    if (e < Ee) rank[e] = atomicAdd(&degi[ei[Ee + e]], 1);
}

__global__ void k_scan_block(const int* __restrict__ in, int* __restrict__ out,
                             int* __restrict__ partials, int n) {
    __shared__ int s[256];
    int i = blockIdx.x * 256 + threadIdx.x;
    int v = (i < n) ? in[i] : 0;
    s[threadIdx.x] = v;
    __syncthreads();
    #pragma unroll
    for (int off = 1; off < 256; off <<= 1) {
        int t = (threadIdx.x >= off) ? s[threadIdx.x - off] : 0;
        __syncthreads();
        s[threadIdx.x] += t;
        __syncthreads();
    }
    if (i < n) out[i] = s[threadIdx.x] - v;
    if (partials && threadIdx.x == 255) partials[blockIdx.x] = s[255];
}

__global__ void k_scan_add(int* __restrict__ rowptr, const int* __restrict__ partials,
                           const int* __restrict__ degi, float* __restrict__ deg) {
    int i = blockIdx.x * 256 + threadIdx.x;
    if (i < Nn) {
        rowptr[i] += partials[blockIdx.x];
        deg[i] = (float)(degi[i] + 1);       // +1 self loop
    }
    if (i == 0) rowptr[Nn] = Ee;
}

// atomic-free bucket placement
__global__ void k_fill2(const int* __restrict__ ei, const int* __restrict__ rowptr,
                        const int* __restrict__ rank, int* __restrict__ csr) {
    int e = blockIdx.x * 256 + threadIdx.x;
    if (e >= Ee) return;
    int d = ei[Ee + e];
    csr[rowptr[d] + rank[e]] = e;
}

// easum (bf16, [EA(16)|zeros(16)] per row) + in-place csr edgeid->src conversion
__global__ void k_eaconv(const int* __restrict__ rowptr, int* __restrict__ csr,
                         const int* __restrict__ ei, const float* __restrict__ ea,
                         short* __restrict__ eab) {
    int idx = blockIdx.x * 256 + threadIdx.x;
    int n = idx >> 2, q = idx & 3;
    if (n >= Nn) return;
    int beg = rowptr[n], end = rowptr[n + 1];
    float4 acc = make_float4(1.f, 1.f, 1.f, 1.f);   // self-loop fill=1.0
    for (int p = beg; p < end; ++p) {
        int e = csr[p];
        float4 v = *(const float4*)(ea + (size_t)e * ECc + q * 4);
        acc.x += v.x; acc.y += v.y; acc.z += v.z; acc.w += v.w;
    }
    short4v h;
    h[0] = f2bf(acc.x); h[1] = f2bf(acc.y); h[2] = f2bf(acc.z); h[3] = f2bf(acc.w);
    *(short4v*)(eab + (size_t)n * 32 + q * 4) = h;
    short4v z; z[0] = 0; z[1] = 0; z[2] = 0; z[3] = 0;
    *(short4v*)(eab + (size_t)n * 32 + 16 + q * 4) = z;
    // convert own segment (same wave as the readers above -> no race)
    for (int p = beg + q; p < end; p += 4)
        csr[p] = ei[csr[p]];
}

// ================= one-shot prep: 5 weight transposes + x_in -> bf16 =================
__device__ __forceinline__ void tbf_one(const float* __restrict__ W, short* __restrict__ WT,
                                        int K, int Ncols, int KP, int idx) {
    int c = idx / KP, k = idx % KP;
    WT[(size_t)c * KP + k] = (k < K) ? f2bf(W[(size_t)k * Ncols + c]) : (short)0;
}

__global__ void k_prep(const float* __restrict__ W0, const float* __restrict__ W1,
                       const float* __restrict__ W2, const float* __restrict__ fc1w,
                       const float* __restrict__ fc2w, const float* __restrict__ x_in,
                       short* __restrict__ WT0, short* __restrict__ WT1,
                       short* __restrict__ WT2, short* __restrict__ fc1wT,
                       short* __restrict__ fc2wT, short* __restrict__ xb0) {
    int idx = blockIdx.x * 256 + threadIdx.x;
    if (idx < 20480) { tbf_one(W0, WT0, 144, 128, 160, idx); return; }
    idx -= 20480;
    if (idx < 36864) { tbf_one(W1, WT1, 272, 128, 288, idx); return; }
    idx -= 36864;
    if (idx < 36864) { tbf_one(W2, WT2, 272, 128, 288, idx); return; }
    idx -= 36864;
    if (idx < 32768) { tbf_one(fc1w, fc1wT, 128, 256, 128, idx); return; }
    idx -= 32768;
    if (idx < 8192) { tbf_one(fc2w, fc2wT, 256, 32, 256, idx); return; }
    idx -= 8192;
    if (idx < 400000) {
        float4 a = *(const float4*)(x_in + (size_t)idx * 8);
        float4 b = *(const float4*)(x_in + (size_t)idx * 8 + 4);
        short8 h;
        h[0] = f2bf(a.x); h[1] = f2bf(a.y); h[2] = f2bf(a.z); h[3] = f2bf(a.w);
        h[4] = f2bf(b.x); h[5] = f2bf(b.y); h[6] = f2bf(b.z); h[7] = f2bf(b.w);
        *(short8*)(xb0 + (size_t)idx * 8) = h;
    }
}

// ================= neighbor gather: G[n] = bf16( sum x[src] + x[n] ) =================
template<int CIN>
__global__ __launch_bounds__(256) void k_gather(
    const int* __restrict__ rowptr, const int* __restrict__ csr,
    const short* __restrict__ xb, short* __restrict__ G)
{
    constexpr int TPN = CIN / 8;
    int idx = blockIdx.x * 256 + threadIdx.x;
    int n = idx / TPN, q = idx % TPN;
    if (n >= Nn) return;
    int beg = rowptr[n], end = rowptr[n + 1];
    float acc[8] = {0.f, 0.f, 0.f, 0.f, 0.f, 0.f, 0.f, 0.f};
    int p = beg;
    for (; p + 1 < end; p += 2) {
        int s0 = csr[p], s1 = csr[p + 1];
        short8 v0 = *(const short8*)(xb + (size_t)s0 * CIN + q * 8);
        short8 v1 = *(const short8*)(xb + (size_t)s1 * CIN + q * 8);
        #pragma unroll
        for (int i = 0; i < 8; ++i) acc[i] += bf2f(v0[i]) + bf2f(v1[i]);
    }
    if (p < end) {
        int s0 = csr[p];
        short8 v0 = *(const short8*)(xb + (size_t)s0 * CIN + q * 8);
        #pragma unroll
        for (int i = 0; i < 8; ++i) acc[i] += bf2f(v0[i]);
    }
    short8 xv = *(const short8*)(xb + (size_t)n * CIN + q * 8);
    short8 h;
    #pragma unroll
    for (int i = 0; i < 8; ++i) h[i] = f2bf(acc[i] + bf2f(xv[i]));
    *(short8*)(G + (size_t)n * CIN + q * 8) = h;
}

// ================= split-GEMM layer: acc = deg.(x@Ws) + G@Wn + EA@We; BN/relu =================
template<int CIN>
__global__ __launch_bounds__(256) void k_layer_mfma(
    const short* __restrict__ xs, const short* __restrict__ G,
    const short* __restrict__ eab, const short* __restrict__ WT,
    const float* __restrict__ deg, const float* __restrict__ bias,
    const float* __restrict__ gamma, const float* __restrict__ beta,
    const float* __restrict__ rmean, const float* __restrict__ rvar,
    short* __restrict__ xoutb)
{
    constexpr int KP = 2 * CIN + 32;
    const int wv = threadIdx.x >> 6, lane = threadIdx.x & 63;
    const int lr = lane & 15, lk = lane >> 4;
    const int row0 = blockIdx.x * 128 + wv * 32;
    const short* Xp0 = xs + (size_t)(row0 + lr) * CIN + lk * 8;
    const short* Xp1 = Xp0 + (size_t)16 * CIN;
    const short* Gp0 = G + (size_t)(row0 + lr) * CIN + lk * 8;
    const short* Gp1 = Gp0 + (size_t)16 * CIN;
    const short* Bp  = WT + (size_t)lr * KP + lk * 8;

    f32x4 acc[2][8];
    #pragma unroll
    for (int i = 0; i < 2; ++i)
        #pragma unroll
        for (int j = 0; j < 8; ++j) acc[i][j] = (f32x4){0.f, 0.f, 0.f, 0.f};

    // phase 1: self  x @ Wself  (WT k in [0,CIN))
    #pragma unroll
    for (int k0 = 0; k0 < CIN; k0 += 32) {
        short8 a0 = *(const short8*)(Xp0 + k0);
        short8 a1 = *(const short8*)(Xp1 + k0);
        #pragma unroll
        for (int j = 0; j < 8; ++j) {
            short8 b = *(const short8*)(Bp + (size_t)j * 16 * KP + k0);
            acc[0][j] = __builtin_amdgcn_mfma_f32_16x16x32_bf16(a0, b, acc[0][j], 0, 0, 0);
            acc[1][j] = __builtin_amdgcn_mfma_f32_16x16x32_bf16(a1, b, acc[1][j], 0, 0, 0);
        }
    }
    // per-row deg scale (exact: deg*(x@W) == (deg*x)@W)
    float dgs[2][4];
    #pragma unroll
    for (int rf = 0; rf < 2; ++rf) {
        int rbase = row0 + rf * 16 + lk * 4;
        #pragma unroll
        for (int i = 0; i < 4; ++i)
            dgs[rf][i] = (rbase + i < Nn) ? deg[rbase + i] : 0.f;
    }
    #pragma unroll
    for (int rf = 0; rf < 2; ++rf)
        #pragma unroll
        for (int j = 0; j < 8; ++j)
            #pragma unroll
            for (int i = 0; i < 4; ++i) acc[rf][j][i] *= dgs[rf][i];

    // phase 2: neighbor  G @ Wnbr  (WT k in [CIN,2CIN))
    #pragma unroll
    for (int k0 = 0; k0 < CIN; k0 += 32) {
        short8 a0 = *(const short8*)(Gp0 + k0);
        short8 a1 = *(const short8*)(Gp1 + k0);
        #pragma unroll
        for (int j = 0; j < 8; ++j) {
            short8 b = *(const short8*)(Bp + (size_t)j * 16 * KP + CIN + k0);
            acc[0][j] = __builtin_amdgcn_mfma_f32_16x16x32_bf16(a0, b, acc[0][j], 0, 0, 0);
            acc[1][j] = __builtin_amdgcn_mfma_f32_16x16x32_bf16(a1, b, acc[1][j], 0, 0, 0);
        }
    }
    // phase 3: EA @ Wea  (WT k in [2CIN, 2CIN+32), eab row = [EA|zeros])
    {
        short8 e0 = *(const short8*)(eab + (size_t)(row0 + lr) * 32 + lk * 8);
        short8 e1 = *(const short8*)(eab + (size_t)(row0 + 16 + lr) * 32 + lk * 8);
        #pragma unroll
        for (int j = 0; j < 8; ++j) {
            short8 b = *(const short8*)(Bp + (size_t)j * 16 * KP + 2 * CIN);
            acc[0][j] = __builtin_amdgcn_mfma_f32_16x16x32_bf16(e0, b, acc[0][j], 0, 0, 0);
            acc[1][j] = __builtin_amdgcn_mfma_f32_16x16x32_bf16(e1, b, acc[1][j], 0, 0, 0);
        }
    }

    #pragma unroll
    for (int rf = 0; rf < 2; ++rf) {
        int rbase = row0 + rf * 16 + lk * 4;
        #pragma unroll
        for (int j = 0; j < 8; ++j) {
            int c = j * 16 + lr;
            float bb = bias[c], gm = gamma[c], bt = beta[c], rm = rmean[c];
            float inv = rsqrtf(rvar[c] + 1e-5f);
            #pragma unroll
            for (int i = 0; i < 4; ++i) {
                int r = rbase + i;
                if (r < Nn) {
                    float v = frelu(acc[rf][j][i] + dgs[rf][i] * bb);
                    v = frelu((v - rm) * inv * gm + bt);
                    xoutb[(size_t)r * HC + c] = f2bf(v);
                }
            }
        }
    }
}

// ================= pooling (bf16 x, run-segmented) =================
__global__ void k_pool2(const short* __restrict__ xbf, const int* __restrict__ batch,
                        float* __restrict__ pooled) {
    constexpr int NPG = 64;
    int gid  = (blockIdx.x * 256 + threadIdx.x) >> 5;
    int lane = threadIdx.x & 31;
    int n0 = gid * NPG;
    if (n0 >= Nn) return;
    int nend = min(n0 + NPG, Nn);
    int curg = batch[n0];
    float4 acc = make_float4(0.f, 0.f, 0.f, 0.f);
    for (int n = n0; n < nend; ++n) {
        int g = batch[n];
        if (g != curg) {
            float* p = pooled + (size_t)curg * HC + lane * 4;
            atomicAdd(p + 0, acc.x); atomicAdd(p + 1, acc.y);
            atomicAdd(p + 2, acc.z); atomicAdd(p + 3, acc.w);
            acc = make_float4(0.f, 0.f, 0.f, 0.f);
            curg = g;
        }
        short4v v = *(const short4v*)(xbf + (size_t)n * HC + lane * 4);
        acc.x += bf2f(v[0]); acc.y += bf2f(v[1]);
        acc.z += bf2f(v[2]); acc.w += bf2f(v[3]);
    }
    float* p = pooled + (size_t)curg * HC + lane * 4;
    atomicAdd(p + 0, acc.x); atomicAdd(p + 1, acc.y);
    atomicAdd(p + 2, acc.z); atomicAdd(p + 3, acc.w);
}

// ================= Prow = pooled @ fc1_w[128:,:] + fc1_b (f32) =================
__global__ void k_prow(const float* __restrict__ pooled, const float* __restrict__ fc1w,
                       const float* __restrict__ fc1b, float* __restrict__ prow) {
    int g = blockIdx.x;
    int j = threadIdx.x;
    __shared__ float ps[HC];
    if (j < HC) ps[j] = pooled[(size_t)g * HC + j];
    __syncthreads();
    float v = fc1b[j];
    #pragma unroll 4
    for (int k = 0; k < HC; ++k)
        v += ps[k] * fc1w[(size_t)(HC + k) * MLPc + j];
    prow[(size_t)g * MLPc + j] = v;
}

// ================= fused fc1+fc2 (MFMA, LDS-staged B + h1 reuse) =================
// BM=128, 4 waves. LDS: 64KB = fc1wT [256 rows][256B] swizzled, then h1 [128 rows][512B] swizzled.
__global__ __launch_bounds__(256) void k_fc_mfma(
    const short* __restrict__ xbf, const float* __restrict__ prow,
    const int* __restrict__ batch, const short* __restrict__ fc1wT,  // [256][128]
    const short* __restrict__ fc2wT,                                  // [32][256]
    const float* __restrict__ fc2b, float* __restrict__ out)
{
    __shared__ short8 ldsv[4096];           // 64 KB
    char* lds = (char*)ldsv;
    const int tid = threadIdx.x;
    const int wv = tid >> 6, lane = tid & 63;
    const int lr = lane & 15, lk = lane >> 4;
    const int row0 = blockIdx.x * 128;

    // ---- stage fc1wT -> LDS (rows of 256B, XOR-swizzled 16B slots) ----
    #pragma unroll
    for (int i = 0; i < 16; ++i) {
        int elem = tid + i * 256;            // 16B unit, 4096 total
        int row  = elem >> 4;
        int colb = (elem & 15) << 4;
        short8 v = *(const short8*)(fc1wT + (size_t)elem * 8);
        *(short8*)(lds + row * 256 + (colb ^ ((row & 15) << 4))) = v;
    }
    __syncthreads();

    // ---- phase 1: wave wv owns rows [wv*32, wv*32+32) x 256 cols ----
    f32x4 acc[2][16];
    #pragma unroll
    for (int rf = 0; rf < 2; ++rf)
        #pragma unroll
        for (int j = 0; j < 16; ++j) acc[rf][j] = (f32x4){0.f, 0.f, 0.f, 0.f};

    const short* Ap0 = xbf + (size_t)(row0 + wv * 32 + lr) * HC + lk * 8;
    const short* Ap1 = Ap0 + (size_t)16 * HC;
    #pragma unroll
    for (int k0 = 0; k0 < 128; k0 += 32) {
        short8 a0 = *(const short8*)(Ap0 + k0);
        short8 a1 = *(const short8*)(Ap1 + k0);
        int o = (k0 + lk * 8) * 2;
        #pragma unroll
        for (int j = 0; j < 16; ++j) {
            int brow = j * 16 + lr;
            short8 b = *(const short8*)(lds + brow * 256 + (o ^ ((brow & 15) << 4)));
            acc[0][j] = __builtin_amdgcn_mfma_f32_16x16x32_bf16(a0, b, acc[0][j], 0, 0, 0);
            acc[1][j] = __builtin_amdgcn_mfma_f32_16x16x32_bf16(a1, b, acc[1][j], 0, 0, 0);
        }
    }
    __syncthreads();    // all fc1wT LDS reads done -> reuse LDS for h1

    // ---- h1 = relu(acc + prow[batch]) -> LDS [128 rows][512B] swizzled ----
    const int rl0 = wv * 32 + lk * 4;
    #pragma unroll
    for (int rf = 0; rf < 2; ++rf) {
        #pragma unroll
        for (int i = 0; i < 4; ++i) {
            int rl = rl0 + rf * 16 + i;
            int r  = row0 + rl;
            int g  = (r < Nn) ? batch[r] : 0;
            const float* pr = prow + (size_t)g * MLPc;
            char* hrow = lds + rl * 512;
            int sw = (rl & 15) << 4;
            #pragma unroll
            for (int j = 0; j < 16; ++j) {
                int c = j * 16 + lr;
                float hv = frelu(acc[rf][j][i] + pr[c]);
                *(short*)(hrow + ((c * 2) ^ sw)) = f2bf(hv);
            }
        }
    }
    __syncthreads();

    // ---- phase 2: out[128][32] = h1 @ fc2w + fc2b ----
    f32x4 acc2[2][2];
    #pragma unroll
    for (int rf = 0; rf < 2; ++rf)
        #pragma unroll
        for (int cf = 0; cf < 2; ++cf) acc2[rf][cf] = (f32x4){0.f, 0.f, 0.f, 0.f};

    const int r0l = wv * 32 + lr, r1l = r0l + 16;
    char* h0row = lds + r0l * 512; int sw0 = (r0l & 15) << 4;
    char* h1row = lds + r1l * 512; int sw1 = (r1l & 15) << 4;
    #pragma unroll
    for (int k0 = 0; k0 < 256; k0 += 32) {
        int o = (k0 + lk * 8) * 2;
        short8 a0 = *(const short8*)(h0row + (o ^ sw0));
        short8 a1 = *(const short8*)(h1row + (o ^ sw1));
        #pragma unroll
        for (int cf = 0; cf < 2; ++cf) {
            short8 b = *(const short8*)(fc2wT + (size_t)(cf * 16 + lr) * 256 + k0 + lk * 8);
            acc2[0][cf] = __builtin_amdgcn_mfma_f32_16x16x32_bf16(a0, b, acc2[0][cf], 0, 0, 0);
            acc2[1][cf] = __builtin_amdgcn_mfma_f32_16x16x32_bf16(a1, b, acc2[1][cf], 0, 0, 0);
        }
    }
    #pragma unroll
    for (int rf = 0; rf < 2; ++rf) {
        int rbase = row0 + wv * 32 + rf * 16 + lk * 4;
        #pragma unroll
        for (int cf = 0; cf < 2; ++cf) {
            int c = cf * 16 + lr;
            float bb = fc2b[c];
            #pragma unroll
            for (int i = 0; i < 4; ++i) {
                int r = rbase + i;
                if (r < Nn) out[(size_t)r * NCc + c] = acc2[rf][cf][i] + bb;
            }
        }
    }
}

// ================= launch =================
extern "C" void kernel_launch(void* const* d_in, const int* in_sizes, int n_in,
                              void* d_out, int out_size, void* d_ws, size_t ws_size,
                              hipStream_t stream) {
    const float* x_in  = (const float*)d_in[0];
    const int*   ei    = (const int*)d_in[1];
    const float* ea    = (const float*)d_in[2];
    const int*   batch = (const int*)d_in[3];
    const float* W0 = (const float*)d_in[4];
    const float* b0 = (const float*)d_in[5];
    const float* g0 = (const float*)d_in[6];
    const float* be0 = (const float*)d_in[7];
    const float* rm0 = (const float*)d_in[8];
    const float* rv0 = (const float*)d_in[9];
    const float* W1 = (const float*)d_in[10];
    const float* b1 = (const float*)d_in[11];
    const float* g1 = (const float*)d_in[12];
    const float* be1 = (const float*)d_in[13];
    const float* rm1 = (const float*)d_in[14];
    const float* rv1 = (const float*)d_in[15];
    const float* W2 = (const float*)d_in[16];
    const float* b2 = (const float*)d_in[17];
    const float* g2 = (const float*)d_in[18];
    const float* be2 = (const float*)d_in[19];
    const float* rm2 = (const float*)d_in[20];
    const float* rv2 = (const float*)d_in[21];
    const float* fc1w = (const float*)d_in[22];
    const float* fc1b = (const float*)d_in[23];
    const float* fc2w = (const float*)d_in[24];
    const float* fc2b = (const float*)d_in[25];

    size_t off = 0;
    auto alloc = [&](size_t bytes) {
        void* p = (char*)d_ws + off;
        off += (bytes + 255) & ~(size_t)255;
        return p;
    };
    int*   rowptr   = (int*)alloc((size_t)(Nn + 1) * 4);
    int*   partials = (int*)alloc(256 * 4);
    int*   rank     = (int*)alloc((size_t)Ee * 4);
    int*   degi     = (int*)alloc((size_t)Nn * 4);
    float* deg      = (float*)alloc((size_t)Nn * 4);
    short* eab      = (short*)alloc((size_t)Mpad * 32 * 2);
    short* xb0      = (short*)alloc((size_t)Mpad * INC * 2);
    short* xbA      = (short*)alloc((size_t)Mpad * HC * 2);
    short* xb3      = (short*)alloc((size_t)Mpad * HC * 2);
    short* G        = (short*)alloc((size_t)Mpad * HC * 2);
    short* WT0      = (short*)alloc((size_t)HC * 160 * 2);
    short* WT1      = (short*)alloc((size_t)HC * 288 * 2);
    short* WT2      = (short*)alloc((size_t)HC * 288 * 2);
    short* fc1wT    = (short*)alloc((size_t)MLPc * 128 * 2);
    short* fc2wT    = (short*)alloc((size_t)NCc * 256 * 2);
    float* pooled   = (float*)alloc((size_t)Gg * HC * 4);
    float* prow     = (float*)alloc((size_t)Gg * MLPc * 4);

    int* csr = (int*)d_out;   // 3.2MB in 6.4MB d_out; dead before k_fc writes out

    constexpr int NB = (Nn + 255) / 256;   // 196
    constexpr int EB = (Ee + 255) / 256;

    // ---- CSR build (one atomic pass) ----
    hipMemsetAsync(degi, 0, (size_t)Nn * 4, stream);
    k_rank<<<EB, 256, 0, stream>>>(ei, degi, rank);
    k_scan_block<<<NB, 256, 0, stream>>>(degi, rowptr, partials, Nn);
    k_scan_block<<<1, 256, 0, stream>>>(partials, partials, nullptr, NB);
    k_scan_add<<<NB, 256, 0, stream>>>(rowptr, partials, degi, deg);
    k_fill2<<<EB, 256, 0, stream>>>(ei, rowptr, rank, csr);
    k_eaconv<<<(Nn * 4 + 255) / 256, 256, 0, stream>>>(rowptr, csr, ei, ea, eab);

    // ---- one-shot prep: weights + input cvt ----
    k_prep<<<(535168 + 255) / 256, 256, 0, stream>>>(W0, W1, W2, fc1w, fc2w, x_in,
                                                     WT0, WT1, WT2, fc1wT, fc2wT, xb0);

    const int LGRID = (Mpad + 127) / 128;   // 391

    // ---- layer 0: xb0 -> xbA ----
    k_gather<INC><<<(Nn * (INC / 8) + 255) / 256, 256, 0, stream>>>(rowptr, csr, xb0, G);
    k_layer_mfma<INC><<<LGRID, 256, 0, stream>>>(xb0, G, eab, WT0, deg,
        b0, g0, be0, rm0, rv0, xbA);

    // ---- layer 1: xbA -> xbA (in-place safe: row-partitioned reads) ----
    k_gather<HC><<<(Nn * (HC / 8) + 255) / 256, 256, 0, stream>>>(rowptr, csr, xbA, G);
    k_layer_mfma<HC><<<LGRID, 256, 0, stream>>>(xbA, G, eab, WT1, deg,
        b1, g1, be1, rm1, rv1, xbA);

    // ---- layer 2: xbA -> xb3 ----
    k_gather<HC><<<(Nn * (HC / 8) + 255) / 256, 256, 0, stream>>>(rowptr, csr, xbA, G);
    k_layer_mfma<HC><<<LGRID, 256, 0, stream>>>(xbA, G, eab, WT2, deg,
        b2, g2, be2, rm2, rv2, xb3);

    // ---- pool + Prow ----
    hipMemsetAsync(pooled, 0, (size_t)Gg * HC * 4, stream);
    k_pool2<<<((Nn + 63) / 64 * 32 + 255) / 256, 256, 0, stream>>>(xb3, batch, pooled);
    k_prow<<<Gg, 256, 0, stream>>>(pooled, fc1w, fc1b, prow);

    // ---- fused fc1 + fc2 ----
    k_fc_mfma<<<(Mpad + 127) / 128, 256, 0, stream>>>(xb3, prow, batch, fc1wT, fc2wT,
                                                      fc2b, (float*)d_out);
}

// Round 7
// 301.315 us; speedup vs baseline: 13.8161x; 1.0016x over previous
//
#include <hip/hip_runtime.h>

constexpr int Nn   = 50000;
constexpr int Ee   = 800000;
constexpr int INC  = 64;
constexpr int HC   = 128;
constexpr int ECc  = 16;
constexpr int MLPc = 256;
constexpr int NCc  = 32;
constexpr int Gg   = 512;
constexpr int Mpad = 50048;          // 391*128

typedef __attribute__((ext_vector_type(8))) short short8;
typedef __attribute__((ext_vector_type(4))) short short4v;
typedef __attribute__((ext_vector_type(4))) float f32x4;

__device__ __forceinline__ float frelu(float v) { return v > 0.f ? v : 0.f; }

__device__ __forceinline__ short f2bf(float f) {
    unsigned u = __float_as_uint(f);
    unsigned r = (u + 0x7fffu + ((u >> 16) & 1u)) >> 16;
    return (short)r;
}
__device__ __forceinline__ float bf2f(short s) {
    return __uint_as_float(((unsigned)(unsigned short)s) << 16);
}

// ================= CSR build (single atomic pass) =================
__global__ void k_rank(const int* __restrict__ ei, int* __restrict__ degi,
                       int* __restrict__ rank) {
    int e = blockIdx.x * 256 + threadIdx.x;
    if (e < Ee) rank[e] = atomicAdd(&degi[ei[Ee + e]], 1);
}

__global__ void k_scan_block(const int* __restrict__ in, int* __restrict__ out,
                             int* __restrict__ partials, int n) {
    __shared__ int s[256];
    int i = blockIdx.x * 256 + threadIdx.x;
    int v = (i < n) ? in[i] : 0;
    s[threadIdx.x] = v;
    __syncthreads();
    #pragma unroll
    for (int off = 1; off < 256; off <<= 1) {
        int t = (threadIdx.x >= off) ? s[threadIdx.x - off] : 0;
        __syncthreads();
        s[threadIdx.x] += t;
        __syncthreads();
    }
    if (i < n) out[i] = s[threadIdx.x] - v;
    if (partials && threadIdx.x == 255) partials[blockIdx.x] = s[255];
}

__global__ void k_scan_add(int* __restrict__ rowptr, const int* __restrict__ partials,
                           const int* __restrict__ degi, float* __restrict__ deg) {
    int i = blockIdx.x * 256 + threadIdx.x;
    if (i < Nn) {
        rowptr[i] += partials[blockIdx.x];
        deg[i] = (float)(degi[i] + 1);       // +1 self loop
    }
    if (i == 0) rowptr[Nn] = Ee;
}

// atomic-free bucket placement
__global__ void k_fill2(const int* __restrict__ ei, const int* __restrict__ rowptr,
                        const int* __restrict__ rank, int* __restrict__ csr) {
    int e = blockIdx.x * 256 + threadIdx.x;
    if (e >= Ee) return;
    int d = ei[Ee + e];
    csr[rowptr[d] + rank[e]] = e;
}

// easum (bf16, [EA(16)|zeros(16)] per row) + in-place csr edgeid->src conversion
__global__ void k_eaconv(const int* __restrict__ rowptr, int* __restrict__ csr,
                         const int* __restrict__ ei, const float* __restrict__ ea,
                         short* __restrict__ eab) {
    int idx = blockIdx.x * 256 + threadIdx.x;
    int n = idx >> 2, q = idx & 3;
    if (n >= Nn) return;
    int beg = rowptr[n], end = rowptr[n + 1];
    float4 acc = make_float4(1.f, 1.f, 1.f, 1.f);   // self-loop fill=1.0
    for (int p = beg; p < end; ++p) {
        int e = csr[p];
        float4 v = *(const float4*)(ea + (size_t)e * ECc + q * 4);
        acc.x += v.x; acc.y += v.y; acc.z += v.z; acc.w += v.w;
    }
    short4v h;
    h[0] = f2bf(acc.x); h[1] = f2bf(acc.y); h[2] = f2bf(acc.z); h[3] = f2bf(acc.w);
    *(short4v*)(eab + (size_t)n * 32 + q * 4) = h;
    short4v z; z[0] = 0; z[1] = 0; z[2] = 0; z[3] = 0;
    *(short4v*)(eab + (size_t)n * 32 + 16 + q * 4) = z;
    // convert own segment (same wave as the readers above -> no race)
    for (int p = beg + q; p < end; p += 4)
        csr[p] = ei[csr[p]];
}

// ================= one-shot prep: 5 weight transposes + x_in -> bf16 =================
__device__ __forceinline__ void tbf_one(const float* __restrict__ W, short* __restrict__ WT,
                                        int K, int Ncols, int KP, int idx) {
    int c = idx / KP, k = idx % KP;
    WT[(size_t)c * KP + k] = (k < K) ? f2bf(W[(size_t)k * Ncols + c]) : (short)0;
}

__global__ void k_prep(const float* __restrict__ W0, const float* __restrict__ W1,
                       const float* __restrict__ W2, const float* __restrict__ fc1w,
                       const float* __restrict__ fc2w, const float* __restrict__ x_in,
                       short* __restrict__ WT0, short* __restrict__ WT1,
                       short* __restrict__ WT2, short* __restrict__ fc1wT,
                       short* __restrict__ fc2wT, short* __restrict__ xb0) {
    int idx = blockIdx.x * 256 + threadIdx.x;
    if (idx < 20480) { tbf_one(W0, WT0, 144, 128, 160, idx); return; }
    idx -= 20480;
    if (idx < 36864) { tbf_one(W1, WT1, 272, 128, 288, idx); return; }
    idx -= 36864;
    if (idx < 36864) { tbf_one(W2, WT2, 272, 128, 288, idx); return; }
    idx -= 36864;
    if (idx < 32768) { tbf_one(fc1w, fc1wT, 128, 256, 128, idx); return; }
    idx -= 32768;
    if (idx < 8192) { tbf_one(fc2w, fc2wT, 256, 32, 256, idx); return; }
    idx -= 8192;
    if (idx < 400000) {
        float4 a = *(const float4*)(x_in + (size_t)idx * 8);
        float4 b = *(const float4*)(x_in + (size_t)idx * 8 + 4);
        short8 h;
        h[0] = f2bf(a.x); h[1] = f2bf(a.y); h[2] = f2bf(a.z); h[3] = f2bf(a.w);
        h[4] = f2bf(b.x); h[5] = f2bf(b.y); h[6] = f2bf(b.z); h[7] = f2bf(b.w);
        *(short8*)(xb0 + (size_t)idx * 8) = h;
    }
}

// ================= neighbor gather: G[n] = bf16( sum x[src] + x[n] ) =================
template<int CIN>
__global__ __launch_bounds__(256) void k_gather(
    const int* __restrict__ rowptr, const int* __restrict__ csr,
    const short* __restrict__ xb, short* __restrict__ G)
{
    constexpr int TPN = CIN / 8;
    int idx = blockIdx.x * 256 + threadIdx.x;
    int n = idx / TPN, q = idx % TPN;
    if (n >= Nn) return;
    int beg = rowptr[n], end = rowptr[n + 1];
    float acc[8] = {0.f, 0.f, 0.f, 0.f, 0.f, 0.f, 0.f, 0.f};
    int p = beg;
    for (; p + 1 < end; p += 2) {
        int s0 = csr[p], s1 = csr[p + 1];
        short8 v0 = *(const short8*)(xb + (size_t)s0 * CIN + q * 8);
        short8 v1 = *(const short8*)(xb + (size_t)s1 * CIN + q * 8);
        #pragma unroll
        for (int i = 0; i < 8; ++i) acc[i] += bf2f(v0[i]) + bf2f(v1[i]);
    }
    if (p < end) {
        int s0 = csr[p];
        short8 v0 = *(const short8*)(xb + (size_t)s0 * CIN + q * 8);
        #pragma unroll
        for (int i = 0; i < 8; ++i) acc[i] += bf2f(v0[i]);
    }
    short8 xv = *(const short8*)(xb + (size_t)n * CIN + q * 8);
    short8 h;
    #pragma unroll
    for (int i = 0; i < 8; ++i) h[i] = f2bf(acc[i] + bf2f(xv[i]));
    *(short8*)(G + (size_t)n * CIN + q * 8) = h;
}

// ================= split-GEMM layer: acc = deg.(x@Ws) + G@Wn + EA@We; BN/relu =================
template<int CIN>
__global__ __launch_bounds__(256) void k_layer_mfma(
    const short* __restrict__ xs, const short* __restrict__ G,
    const short* __restrict__ eab, const short* __restrict__ WT,
    const float* __restrict__ deg, const float* __restrict__ bias,
    const float* __restrict__ gamma, const float* __restrict__ beta,
    const float* __restrict__ rmean, const float* __restrict__ rvar,
    short* __restrict__ xoutb)
{
    constexpr int KP = 2 * CIN + 32;
    const int wv = threadIdx.x >> 6, lane = threadIdx.x & 63;
    const int lr = lane & 15, lk = lane >> 4;
    const int row0 = blockIdx.x * 128 + wv * 32;
    const short* Xp0 = xs + (size_t)(row0 + lr) * CIN + lk * 8;
    const short* Xp1 = Xp0 + (size_t)16 * CIN;
    const short* Gp0 = G + (size_t)(row0 + lr) * CIN + lk * 8;
    const short* Gp1 = Gp0 + (size_t)16 * CIN;
    const short* Bp  = WT + (size_t)lr * KP + lk * 8;

    f32x4 acc[2][8];
    #pragma unroll
    for (int i = 0; i < 2; ++i)
        #pragma unroll
        for (int j = 0; j < 8; ++j) acc[i][j] = (f32x4){0.f, 0.f, 0.f, 0.f};

    // phase 1: self  x @ Wself  (WT k in [0,CIN))
    #pragma unroll
    for (int k0 = 0; k0 < CIN; k0 += 32) {
        short8 a0 = *(const short8*)(Xp0 + k0);
        short8 a1 = *(const short8*)(Xp1 + k0);
        #pragma unroll
        for (int j = 0; j < 8; ++j) {
            short8 b = *(const short8*)(Bp + (size_t)j * 16 * KP + k0);
            acc[0][j] = __builtin_amdgcn_mfma_f32_16x16x32_bf16(a0, b, acc[0][j], 0, 0, 0);
            acc[1][j] = __builtin_amdgcn_mfma_f32_16x16x32_bf16(a1, b, acc[1][j], 0, 0, 0);
        }
    }
    // per-row deg scale (exact: deg*(x@W) == (deg*x)@W)
    float dgs[2][4];
    #pragma unroll
    for (int rf = 0; rf < 2; ++rf) {
        int rbase = row0 + rf * 16 + lk * 4;
        #pragma unroll
        for (int i = 0; i < 4; ++i)
            dgs[rf][i] = (rbase + i < Nn) ? deg[rbase + i] : 0.f;
    }
    #pragma unroll
    for (int rf = 0; rf < 2; ++rf)
        #pragma unroll
        for (int j = 0; j < 8; ++j)
            #pragma unroll
            for (int i = 0; i < 4; ++i) acc[rf][j][i] *= dgs[rf][i];

    // phase 2: neighbor  G @ Wnbr  (WT k in [CIN,2CIN))
    #pragma unroll
    for (int k0 = 0; k0 < CIN; k0 += 32) {
        short8 a0 = *(const short8*)(Gp0 + k0);
        short8 a1 = *(const short8*)(Gp1 + k0);
        #pragma unroll
        for (int j = 0; j < 8; ++j) {
            short8 b = *(const short8*)(Bp + (size_t)j * 16 * KP + CIN + k0);
            acc[0][j] = __builtin_amdgcn_mfma_f32_16x16x32_bf16(a0, b, acc[0][j], 0, 0, 0);
            acc[1][j] = __builtin_amdgcn_mfma_f32_16x16x32_bf16(a1, b, acc[1][j], 0, 0, 0);
        }
    }
    // phase 3: EA @ Wea  (WT k in [2CIN, 2CIN+32), eab row = [EA|zeros])
    {
        short8 e0 = *(const short8*)(eab + (size_t)(row0 + lr) * 32 + lk * 8);
        short8 e1 = *(const short8*)(eab + (size_t)(row0 + 16 + lr) * 32 + lk * 8);
        #pragma unroll
        for (int j = 0; j < 8; ++j) {
            short8 b = *(const short8*)(Bp + (size_t)j * 16 * KP + 2 * CIN);
            acc[0][j] = __builtin_amdgcn_mfma_f32_16x16x32_bf16(e0, b, acc[0][j], 0, 0, 0);
            acc[1][j] = __builtin_amdgcn_mfma_f32_16x16x32_bf16(e1, b, acc[1][j], 0, 0, 0);
        }
    }

    #pragma unroll
    for (int rf = 0; rf < 2; ++rf) {
        int rbase = row0 + rf * 16 + lk * 4;
        #pragma unroll
        for (int j = 0; j < 8; ++j) {
            int c = j * 16 + lr;
            float bb = bias[c], gm = gamma[c], bt = beta[c], rm = rmean[c];
            float inv = rsqrtf(rvar[c] + 1e-5f);
            #pragma unroll
            for (int i = 0; i < 4; ++i) {
                int r = rbase + i;
                if (r < Nn) {
                    float v = frelu(acc[rf][j][i] + dgs[rf][i] * bb);
                    v = frelu((v - rm) * inv * gm + bt);
                    xoutb[(size_t)r * HC + c] = f2bf(v);
                }
            }
        }
    }
}

// ================= pooling (bf16 x, run-segmented) =================
__global__ void k_pool2(const short* __restrict__ xbf, const int* __restrict__ batch,
                        float* __restrict__ pooled) {
    constexpr int NPG = 64;
    int gid  = (blockIdx.x * 256 + threadIdx.x) >> 5;
    int lane = threadIdx.x & 31;
    int n0 = gid * NPG;
    if (n0 >= Nn) return;
    int nend = min(n0 + NPG, Nn);
    int curg = batch[n0];
    float4 acc = make_float4(0.f, 0.f, 0.f, 0.f);
    for (int n = n0; n < nend; ++n) {
        int g = batch[n];
        if (g != curg) {
            float* p = pooled + (size_t)curg * HC + lane * 4;
            atomicAdd(p + 0, acc.x); atomicAdd(p + 1, acc.y);
            atomicAdd(p + 2, acc.z); atomicAdd(p + 3, acc.w);
            acc = make_float4(0.f, 0.f, 0.f, 0.f);
            curg = g;
        }
        short4v v = *(const short4v*)(xbf + (size_t)n * HC + lane * 4);
        acc.x += bf2f(v[0]); acc.y += bf2f(v[1]);
        acc.z += bf2f(v[2]); acc.w += bf2f(v[3]);
    }
    float* p = pooled + (size_t)curg * HC + lane * 4;
    atomicAdd(p + 0, acc.x); atomicAdd(p + 1, acc.y);
    atomicAdd(p + 2, acc.z); atomicAdd(p + 3, acc.w);
}

// ================= Prow = pooled @ fc1_w[128:,:] + fc1_b -> bf16 =================
__global__ void k_prow(const float* __restrict__ pooled, const float* __restrict__ fc1w,
                       const float* __restrict__ fc1b, short* __restrict__ prowb) {
    int g = blockIdx.x;
    int j = threadIdx.x;
    __shared__ float ps[HC];
    if (j < HC) ps[j] = pooled[(size_t)g * HC + j];
    __syncthreads();
    float v = fc1b[j];
    #pragma unroll 4
    for (int k = 0; k < HC; ++k)
        v += ps[k] * fc1w[(size_t)(HC + k) * MLPc + j];
    prowb[(size_t)g * MLPc + j] = f2bf(v);
}

// ================= fused fc1+fc2 (MFMA, 8 waves, vectorized prow pass) =================
// BM=128, 512 threads. LDS 64KB = fc1wT [256r][256B] swz, then h1 [128r][512B] swz.
__global__ __launch_bounds__(512) void k_fc_mfma(
    const short* __restrict__ xbf, const short* __restrict__ prowb,
    const int* __restrict__ batch, const short* __restrict__ fc1wT,  // [256][128]
    const short* __restrict__ fc2wT,                                  // [32][256]
    const float* __restrict__ fc2b, float* __restrict__ out)
{
    __shared__ short8 ldsv[4096];           // 64 KB
    char* lds = (char*)ldsv;
    const int tid = threadIdx.x;
    const int wv = tid >> 6, lane = tid & 63;
    const int lr = lane & 15, lk = lane >> 4;
    const int row0 = blockIdx.x * 128;

    // ---- A prefetch (issue before staging; hides L3 latency under stage+sync) ----
    const short* Ap = xbf + (size_t)(row0 + wv * 16 + lr) * HC + lk * 8;
    short8 a0 = *(const short8*)(Ap + 0);
    short8 a1 = *(const short8*)(Ap + 32);
    short8 a2 = *(const short8*)(Ap + 64);
    short8 a3 = *(const short8*)(Ap + 96);

    // ---- stage fc1wT -> LDS (rows of 256B, XOR-swizzled 16B slots) ----
    #pragma unroll
    for (int i = 0; i < 8; ++i) {
        int elem = tid + i * 512;            // 16B unit, 4096 total
        int row  = elem >> 4;
        int colb = (elem & 15) << 4;
        short8 v = *(const short8*)(fc1wT + (size_t)elem * 8);
        *(short8*)(lds + row * 256 + (colb ^ ((row & 15) << 4))) = v;
    }
    __syncthreads();

    // ---- phase 1: wave wv owns rows [wv*16, wv*16+16) x 256 cols ----
    f32x4 acc[16];
    #pragma unroll
    for (int j = 0; j < 16; ++j) acc[j] = (f32x4){0.f, 0.f, 0.f, 0.f};
    short8 av[4] = {a0, a1, a2, a3};
    #pragma unroll
    for (int k = 0; k < 4; ++k) {
        int o = (k * 32 + lk * 8) * 2;
        #pragma unroll
        for (int j = 0; j < 16; ++j) {
            int brow = j * 16 + lr;
            short8 b = *(const short8*)(lds + brow * 256 + (o ^ ((brow & 15) << 4)));
            acc[j] = __builtin_amdgcn_mfma_f32_16x16x32_bf16(av[k], b, acc[j], 0, 0, 0);
        }
    }
    __syncthreads();    // fc1wT LDS reads done -> reuse LDS for h1

    // ---- raw acc -> h1 LDS bf16 (no prow yet) ----
    const int rl0 = wv * 16 + lk * 4;
    #pragma unroll
    for (int j = 0; j < 16; ++j) {
        int c = j * 16 + lr;
        #pragma unroll
        for (int i = 0; i < 4; ++i) {
            int rl = rl0 + i;
            *(short*)(lds + rl * 512 + ((c * 2) ^ ((rl & 15) << 4))) = f2bf(acc[j][i]);
        }
    }
    __syncthreads();

    // ---- vectorized prow add + relu: thread t -> row t>>2, quarter t&3 ----
    {
        int rl = tid >> 2, qq = tid & 3;
        int r = row0 + rl;
        if (r < Nn) {
            int g = batch[r];
            const short* pr = prowb + (size_t)g * MLPc + qq * 64;
            int sw = (rl & 15) << 4;
            char* hrow = lds + rl * 512;
            #pragma unroll
            for (int jj = 0; jj < 8; ++jj) {
                int c0 = qq * 64 + jj * 8;
                short8 pv = *(const short8*)(pr + jj * 8);
                short8 hv = *(const short8*)(hrow + ((c0 * 2) ^ sw));
                short8 ho;
                #pragma unroll
                for (int u = 0; u < 8; ++u)
                    ho[u] = f2bf(frelu(bf2f(hv[u]) + bf2f(pv[u])));
                *(short8*)(hrow + ((c0 * 2) ^ sw)) = ho;
            }
        }
    }
    __syncthreads();

    // ---- phase 2: out[128][32] = h1 @ fc2w + fc2b ----
    f32x4 acc2[2];
    acc2[0] = (f32x4){0.f, 0.f, 0.f, 0.f};
    acc2[1] = (f32x4){0.f, 0.f, 0.f, 0.f};
    const int r0l = wv * 16 + lr;
    const char* hrow = lds + r0l * 512;
    const int sw0 = (r0l & 15) << 4;
    #pragma unroll
    for (int k0 = 0; k0 < 256; k0 += 32) {
        int o = (k0 + lk * 8) * 2;
        short8 a = *(const short8*)(hrow + (o ^ sw0));
        #pragma unroll
        for (int cf = 0; cf < 2; ++cf) {
            short8 b = *(const short8*)(fc2wT + (size_t)(cf * 16 + lr) * 256 + k0 + lk * 8);
            acc2[cf] = __builtin_amdgcn_mfma_f32_16x16x32_bf16(a, b, acc2[cf], 0, 0, 0);
        }
    }
    const int rbase = row0 + wv * 16 + lk * 4;
    #pragma unroll
    for (int cf = 0; cf < 2; ++cf) {
        int c = cf * 16 + lr;
        float bb = fc2b[c];
        #pragma unroll
        for (int i = 0; i < 4; ++i) {
            int r = rbase + i;
            if (r < Nn) out[(size_t)r * NCc + c] = acc2[cf][i] + bb;
        }
    }
}

// ================= launch =================
extern "C" void kernel_launch(void* const* d_in, const int* in_sizes, int n_in,
                              void* d_out, int out_size, void* d_ws, size_t ws_size,
                              hipStream_t stream) {
    const float* x_in  = (const float*)d_in[0];
    const int*   ei    = (const int*)d_in[1];
    const float* ea    = (const float*)d_in[2];
    const int*   batch = (const int*)d_in[3];
    const float* W0 = (const float*)d_in[4];
    const float* b0 = (const float*)d_in[5];
    const float* g0 = (const float*)d_in[6];
    const float* be0 = (const float*)d_in[7];
    const float* rm0 = (const float*)d_in[8];
    const float* rv0 = (const float*)d_in[9];
    const float* W1 = (const float*)d_in[10];
    const float* b1 = (const float*)d_in[11];
    const float* g1 = (const float*)d_in[12];
    const float* be1 = (const float*)d_in[13];
    const float* rm1 = (const float*)d_in[14];
    const float* rv1 = (const float*)d_in[15];
    const float* W2 = (const float*)d_in[16];
    const float* b2 = (const float*)d_in[17];
    const float* g2 = (const float*)d_in[18];
    const float* be2 = (const float*)d_in[19];
    const float* rm2 = (const float*)d_in[20];
    const float* rv2 = (const float*)d_in[21];
    const float* fc1w = (const float*)d_in[22];
    const float* fc1b = (const float*)d_in[23];
    const float* fc2w = (const float*)d_in[24];
    const float* fc2b = (const float*)d_in[25];

    size_t off = 0;
    auto alloc = [&](size_t bytes) {
        void* p = (char*)d_ws + off;
        off += (bytes + 255) & ~(size_t)255;
        return p;
    };
    int*   rowptr   = (int*)alloc((size_t)(Nn + 1) * 4);
    int*   partials = (int*)alloc(256 * 4);
    int*   rank     = (int*)alloc((size_t)Ee * 4);
    int*   degi     = (int*)alloc((size_t)Nn * 4);
    float* deg      = (float*)alloc((size_t)Nn * 4);
    short* eab      = (short*)alloc((size_t)Mpad * 32 * 2);
    short* xb0      = (short*)alloc((size_t)Mpad * INC * 2);
    short* xbA      = (short*)alloc((size_t)Mpad * HC * 2);
    short* xb3      = (short*)alloc((size_t)Mpad * HC * 2);
    short* G        = (short*)alloc((size_t)Mpad * HC * 2);
    short* WT0      = (short*)alloc((size_t)HC * 160 * 2);
    short* WT1      = (short*)alloc((size_t)HC * 288 * 2);
    short* WT2      = (short*)alloc((size_t)HC * 288 * 2);
    short* fc1wT    = (short*)alloc((size_t)MLPc * 128 * 2);
    short* fc2wT    = (short*)alloc((size_t)NCc * 256 * 2);
    float* pooled   = (float*)alloc((size_t)Gg * HC * 4);
    short* prowb    = (short*)alloc((size_t)Gg * MLPc * 2);

    int* csr = (int*)d_out;   // 3.2MB in 6.4MB d_out; dead before k_fc writes out

    constexpr int NB = (Nn + 255) / 256;   // 196
    constexpr int EB = (Ee + 255) / 256;

    // ---- CSR build (one atomic pass) ----
    hipMemsetAsync(degi, 0, (size_t)Nn * 4, stream);
    k_rank<<<EB, 256, 0, stream>>>(ei, degi, rank);
    k_scan_block<<<NB, 256, 0, stream>>>(degi, rowptr, partials, Nn);
    k_scan_block<<<1, 256, 0, stream>>>(partials, partials, nullptr, NB);
    k_scan_add<<<NB, 256, 0, stream>>>(rowptr, partials, degi, deg);
    k_fill2<<<EB, 256, 0, stream>>>(ei, rowptr, rank, csr);
    k_eaconv<<<(Nn * 4 + 255) / 256, 256, 0, stream>>>(rowptr, csr, ei, ea, eab);

    // ---- one-shot prep: weights + input cvt ----
    k_prep<<<(535168 + 255) / 256, 256, 0, stream>>>(W0, W1, W2, fc1w, fc2w, x_in,
                                                     WT0, WT1, WT2, fc1wT, fc2wT, xb0);

    const int LGRID = (Mpad + 127) / 128;   // 391

    // ---- layer 0: xb0 -> xbA ----
    k_gather<INC><<<(Nn * (INC / 8) + 255) / 256, 256, 0, stream>>>(rowptr, csr, xb0, G);
    k_layer_mfma<INC><<<LGRID, 256, 0, stream>>>(xb0, G, eab, WT0, deg,
        b0, g0, be0, rm0, rv0, xbA);

    // ---- layer 1: xbA -> xbA (in-place safe: row-partitioned reads) ----
    k_gather<HC><<<(Nn * (HC / 8) + 255) / 256, 256, 0, stream>>>(rowptr, csr, xbA, G);
    k_layer_mfma<HC><<<LGRID, 256, 0, stream>>>(xbA, G, eab, WT1, deg,
        b1, g1, be1, rm1, rv1, xbA);

    // ---- layer 2: xbA -> xb3 ----
    k_gather<HC><<<(Nn * (HC / 8) + 255) / 256, 256, 0, stream>>>(rowptr, csr, xbA, G);
    k_layer_mfma<HC><<<LGRID, 256, 0, stream>>>(xbA, G, eab, WT2, deg,
        b2, g2, be2, rm2, rv2, xb3);

    // ---- pool + Prow (bf16) ----
    hipMemsetAsync(pooled, 0, (size_t)Gg * HC * 4, stream);
    k_pool2<<<((Nn + 63) / 64 * 32 + 255) / 256, 256, 0, stream>>>(xb3, batch, pooled);
    k_prow<<<Gg, 256, 0, stream>>>(pooled, fc1w, fc1b, prowb);

    // ---- fused fc1 + fc2 ----
    k_fc_mfma<<<(Mpad + 127) / 128, 512, 0, stream>>>(xb3, prowb, batch, fc1wT, fc2wT,
                                                      fc2b, (float*)d_out);
}